// Round 3
// baseline (215.925 us; speedup 1.0000x reference)
//
#include <hip/hip_runtime.h>
#include <hip/hip_bf16.h>

// Problem constants (B, C, T, H, KC, WIN) = (4, 512, 1024, 8, 64, 4)
#define Bdim 4
#define Cdim 512
#define Tdim 1024
#define Hn   8
#define KCd  64

// softmax scale folded into q: 1/sqrt(KC) * log2(e) -> scores in exp2 domain
#define QK_SCALE 0.18033688011112042f

typedef __attribute__((ext_vector_type(8))) short bf16x8;   // 8 bf16 = 4 VGPR
typedef __attribute__((ext_vector_type(4))) float f32x4;    // MFMA C/D

__device__ __forceinline__ unsigned short f32_bf16_rne(float f) {
    unsigned u = __float_as_uint(f);
    u += 0x7FFFu + ((u >> 16) & 1u);
    return (unsigned short)(u >> 16);
}
__device__ __forceinline__ float bf16_f32(unsigned short h) {
    return __uint_as_float(((unsigned)h) << 16);
}
__device__ __forceinline__ void split8(const float* f, bf16x8& h8, bf16x8& l8) {
    #pragma unroll
    for (int e = 0; e < 8; ++e) {
        const unsigned short hh = f32_bf16_rne(f[e]);
        h8[e] = (short)hh;
        l8[e] = (short)f32_bf16_rne(f[e] - bf16_f32(hh));
    }
}

// LDS 64x64 tile XOR swizzle (only attention's P round-trip)
__device__ __forceinline__ int sw(int row, int col) {
    return (row << 6) + ((((col >> 3) ^ (row & 7)) << 3) | (col & 7));
}
__device__ __forceinline__ bf16x8 fragld(const unsigned short* a, int row, int kstep, int quad) {
    return *(const bf16x8*)&a[(row << 6) + ((((kstep << 2) | quad) ^ (row & 7)) << 3)];
}

// ---------------------------------------------------------------------------
// FRAG-MAJOR plane layouts (hi/lo pre-split), as validated in R8/R9:
//  A-plane (stacked [wq;wk;wv;wo], 2048 rows x 512 k):
//    [mtile16:128][kt:16][lane:64][e:8]; elem(m,k): lane=((k>>3)&3)*16+(m&15), e=k&7
//  B-plane (X / ctx, per batch n=1024, k=512):
//    [b*64+ntile16][kt:16][lane:64][e:8]; elem(n,k): lane=((k>>3)&3)*16+(n&15), e=k&7
//  Attn planes per (b,h), 16 time-tiles of 64x64:
//    row-type (Q,K): g=(t>>4)*2+(c>>5), lane=((c>>3)&3)*16+(t&15), e=c&7
//    col-type (V):   g=(c>>4)*2+(t>>5), lane=((t>>3)&3)*16+(c&15), e=t&7
// ---------------------------------------------------------------------------

// prep: one-time fp32 -> hi/lo split into A/B planes (R9, measured good)
__global__ __launch_bounds__(256) void prep_kernel(
    const float* __restrict__ wq, const float* __restrict__ wk,
    const float* __restrict__ wv, const float* __restrict__ wo,
    const float* __restrict__ x,
    unsigned short* __restrict__ WAhi, unsigned short* __restrict__ WAlo,
    unsigned short* __restrict__ XBhi, unsigned short* __restrict__ XBlo)
{
    const int w = threadIdx.x >> 6, lane = threadIdx.x & 63;
    const int l15 = lane & 15, quad = lane >> 4;
    const int task = blockIdx.x * 4 + w;

    if (task < 2048) {
        const int mtile = task >> 4, kt = task & 15;
        const int sel = mtile >> 5;
        const float* W = sel == 0 ? wq : (sel == 1 ? wk : (sel == 2 ? wv : wo));
        const int row = (mtile & 31) * 16 + l15;
        const float* p = W + (size_t)row * Cdim + kt * 32 + quad * 8;
        float f[8];
        *(float4*)&f[0] = *(const float4*)p;
        *(float4*)&f[4] = *(const float4*)(p + 4);
        bf16x8 h8, l8;
        split8(f, h8, l8);
        const size_t base = (size_t)task * 512 + lane * 8;
        *(bf16x8*)(WAhi + base) = h8;
        *(bf16x8*)(WAlo + base) = l8;
    } else {
        const int t2 = task - 2048;
        const int b = t2 >> 10, ntile = (t2 >> 4) & 63, kt = t2 & 15;
        const float* Xb = x + (size_t)b * Cdim * Tdim;
        const int n = ntile * 16 + l15;
        const int k0 = kt * 32 + quad * 8;
        float f[8];
        #pragma unroll
        for (int e = 0; e < 8; ++e) f[e] = Xb[(size_t)(k0 + e) * Tdim + n];
        bf16x8 h8, l8;
        split8(f, h8, l8);
        const size_t base = (size_t)t2 * 512 + lane * 8;
        *(bf16x8*)(XBhi + base) = h8;
        *(bf16x8*)(XBlo + base) = l8;
    }
}

// ---------------------------------------------------------------------------
// QKV GEMM: barrier-free, zero-LDS, dbuf. Wave = 64m x 32n x 512k.
// 3072 wave-jobs -> 768 blocks = 3 blocks/CU (12 waves/CU).
// XCD-clustered: 16 (b,n32) columns per XCD share B stripes in that L2.
// q rows are pre-scaled by QK_SCALE so attention scores land in exp2 domain.
// ---------------------------------------------------------------------------
__global__ __launch_bounds__(256, 3) void gemm_qkv(
    const unsigned short* __restrict__ Ahi, const unsigned short* __restrict__ Alo,
    const unsigned short* __restrict__ Bhi, const unsigned short* __restrict__ Blo,
    const float* __restrict__ bq, const float* __restrict__ bk, const float* __restrict__ bv,
    unsigned short* __restrict__ qhi, unsigned short* __restrict__ qlo,
    unsigned short* __restrict__ khi, unsigned short* __restrict__ klo,
    unsigned short* __restrict__ vhi, unsigned short* __restrict__ vlo)
{
    const int tid = threadIdx.x;
    const int w = tid >> 6, lane = tid & 63;
    const int l15 = lane & 15, quad = lane >> 4;
    const int lo8 = lane << 3;

    const int id = blockIdx.x;
    const int xcd = id & 7, slot = id >> 3;     // slot 0..95
    const int col = xcd * 16 + slot / 6;        // 0..127 = (b, n32)
    const int mg  = slot % 6;
    const int b = col >> 5, n32 = col & 31;
    const int m64 = mg * 4 + w;                 // 0..23 stacked q/k/v
    const int sel = m64 >> 3;
    const int mtb = m64 * 4;                    // mtile16 base (q:0-31 k:32-63 v:64-95)
    const int ntb = b * 64 + n32 * 2;

    f32x4 acc[4][2];
    #pragma unroll
    for (int i = 0; i < 4; ++i)
        #pragma unroll
        for (int j = 0; j < 2; ++j) acc[i][j] = (f32x4){0.f, 0.f, 0.f, 0.f};

    bf16x8 Ah[2][4], Al[2][4], Bh[2][2], Bl[2][2];
    #pragma unroll
    for (int mt = 0; mt < 4; ++mt) {
        const size_t o = (size_t)(mtb + mt) * 8192 + lo8;
        Ah[0][mt] = *(const bf16x8*)(Ahi + o);
        Al[0][mt] = *(const bf16x8*)(Alo + o);
    }
    #pragma unroll
    for (int nt = 0; nt < 2; ++nt) {
        const size_t o = (size_t)(ntb + nt) * 8192 + lo8;
        Bh[0][nt] = *(const bf16x8*)(Bhi + o);
        Bl[0][nt] = *(const bf16x8*)(Blo + o);
    }

    for (int kt = 0; kt < 16; ++kt) {
        const int cur = kt & 1, nxt = cur ^ 1;
        if (kt < 15) {
            const int kn = (kt + 1) * 512;
            #pragma unroll
            for (int mt = 0; mt < 4; ++mt) {
                const size_t o = (size_t)(mtb + mt) * 8192 + kn + lo8;
                Ah[nxt][mt] = *(const bf16x8*)(Ahi + o);
                Al[nxt][mt] = *(const bf16x8*)(Alo + o);
            }
            #pragma unroll
            for (int nt = 0; nt < 2; ++nt) {
                const size_t o = (size_t)(ntb + nt) * 8192 + kn + lo8;
                Bh[nxt][nt] = *(const bf16x8*)(Bhi + o);
                Bl[nxt][nt] = *(const bf16x8*)(Blo + o);
            }
        }
        #pragma unroll
        for (int mt = 0; mt < 4; ++mt)
            #pragma unroll
            for (int nt = 0; nt < 2; ++nt) {
                f32x4 c = acc[mt][nt];
                c = __builtin_amdgcn_mfma_f32_16x16x32_bf16(Ah[cur][mt], Bh[cur][nt], c, 0, 0, 0);
                c = __builtin_amdgcn_mfma_f32_16x16x32_bf16(Ah[cur][mt], Bl[cur][nt], c, 0, 0, 0);
                c = __builtin_amdgcn_mfma_f32_16x16x32_bf16(Al[cur][mt], Bh[cur][nt], c, 0, 0, 0);
                acc[mt][nt] = c;
            }
    }

    // ---- epilogue: D[m=quad*4+r (channel)][n=l15 (time)] -> attn planes ----
    const int head = m64 & 7;
    const size_t hbase = ((size_t)(b * Hn + head) * 16) << 12;
    if (sel < 2) {
        const float* Bv = sel == 0 ? bq : bk;
        unsigned short* ph = sel == 0 ? qhi : khi;
        unsigned short* pl = sel == 0 ? qlo : klo;
        const float qscale = sel == 0 ? QK_SCALE : 1.0f;
        #pragma unroll
        for (int mt = 0; mt < 4; ++mt) {
            const int c0 = mt * 16 + quad * 4;          // channel-in-head base
            float bb[4];
            #pragma unroll
            for (int r = 0; r < 4; ++r) bb[r] = Bv[head * 64 + c0 + r];
            const int lane_out = (((c0 >> 3) & 3) << 4) + l15;
            const int e0 = c0 & 7;                      // 0 or 4
            const int cg = c0 >> 5;
            #pragma unroll
            for (int nt = 0; nt < 2; ++nt) {
                const int tile = n32 >> 1;
                const int rhi = (n32 & 1) * 2 + nt;     // (t&63)>>4
                const int g = rhi * 2 + cg;
                const size_t off = hbase + ((size_t)tile << 12) + g * 512
                                 + (size_t)lane_out * 8 + e0;
                ushort4 h4, l4;
                #pragma unroll
                for (int r = 0; r < 4; ++r) {
                    const float v = (acc[mt][nt][r] + bb[r]) * qscale;
                    const unsigned short hh = f32_bf16_rne(v);
                    ((unsigned short*)&h4)[r] = hh;
                    ((unsigned short*)&l4)[r] = f32_bf16_rne(v - bf16_f32(hh));
                }
                *(ushort4*)(ph + off) = h4;
                *(ushort4*)(pl + off) = l4;
            }
        }
    } else {
        #pragma unroll
        for (int mt = 0; mt < 4; ++mt) {
            const int c0 = mt * 16 + quad * 4;
            float bb[4];
            #pragma unroll
            for (int r = 0; r < 4; ++r) bb[r] = bv[head * 64 + c0 + r];
            #pragma unroll
            for (int nt = 0; nt < 2; ++nt) {
                const int t = n32 * 32 + nt * 16 + l15;
                const int tile = t >> 6, jl = t & 63;
                const int jg = jl >> 5, lanej = ((jl >> 3) & 3) << 4;
                const int e = jl & 7;
                const size_t tb = hbase + ((size_t)tile << 12);
                #pragma unroll
                for (int r = 0; r < 4; ++r) {
                    const int c = c0 + r;
                    const int g = mt * 2 + jg;          // c>>4 == mt here
                    const int lane_v = lanej + (c & 15);
                    const float v = acc[mt][nt][r] + bb[r];
                    const unsigned short hh = f32_bf16_rne(v);
                    const size_t off = tb + g * 512 + (size_t)lane_v * 8 + e;
                    vhi[off] = hh;
                    vlo[off] = f32_bf16_rne(v - bf16_f32(hh));
                }
            }
        }
    }
}

// ---------------------------------------------------------------------------
// Out-projection GEMM: barrier-free, zero-LDS, dbuf. Wave = 32m x 32n x 512k.
// 2048 wave-jobs -> 512 blocks = 2 blocks/CU (every CU active).
// A = Wo rows (mtile16 96..127), B = ctx planes from attention.
// ---------------------------------------------------------------------------
__global__ __launch_bounds__(256) void gemm_out(
    const unsigned short* __restrict__ Ahi, const unsigned short* __restrict__ Alo,
    const unsigned short* __restrict__ Bhi, const unsigned short* __restrict__ Blo,
    const float* __restrict__ bo, float* __restrict__ out)
{
    const int tid = threadIdx.x;
    const int w = tid >> 6, lane = tid & 63;
    const int l15 = lane & 15, quad = lane >> 4;
    const int lo8 = lane << 3;

    const int id = blockIdx.x;
    const int xcd = id & 7, slot = id >> 3;     // slot 0..63
    const int col = xcd * 16 + (slot >> 2);     // 0..127 = (b, n32)
    const int mg  = slot & 3;
    const int b = col >> 5, n32 = col & 31;
    const int m32 = mg * 4 + w;                 // 0..15
    const int mtb = 96 + m32 * 2;               // Wo mtile16 base
    const int ntb = b * 64 + n32 * 2;

    f32x4 acc[2][2];
    #pragma unroll
    for (int i = 0; i < 2; ++i)
        #pragma unroll
        for (int j = 0; j < 2; ++j) acc[i][j] = (f32x4){0.f, 0.f, 0.f, 0.f};

    bf16x8 Ah[2][2], Al[2][2], Bh[2][2], Bl[2][2];
    #pragma unroll
    for (int mt = 0; mt < 2; ++mt) {
        const size_t o = (size_t)(mtb + mt) * 8192 + lo8;
        Ah[0][mt] = *(const bf16x8*)(Ahi + o);
        Al[0][mt] = *(const bf16x8*)(Alo + o);
    }
    #pragma unroll
    for (int nt = 0; nt < 2; ++nt) {
        const size_t o = (size_t)(ntb + nt) * 8192 + lo8;
        Bh[0][nt] = *(const bf16x8*)(Bhi + o);
        Bl[0][nt] = *(const bf16x8*)(Blo + o);
    }

    for (int kt = 0; kt < 16; ++kt) {
        const int cur = kt & 1, nxt = cur ^ 1;
        if (kt < 15) {
            const int kn = (kt + 1) * 512;
            #pragma unroll
            for (int mt = 0; mt < 2; ++mt) {
                const size_t o = (size_t)(mtb + mt) * 8192 + kn + lo8;
                Ah[nxt][mt] = *(const bf16x8*)(Ahi + o);
                Al[nxt][mt] = *(const bf16x8*)(Alo + o);
            }
            #pragma unroll
            for (int nt = 0; nt < 2; ++nt) {
                const size_t o = (size_t)(ntb + nt) * 8192 + kn + lo8;
                Bh[nxt][nt] = *(const bf16x8*)(Bhi + o);
                Bl[nxt][nt] = *(const bf16x8*)(Blo + o);
            }
        }
        #pragma unroll
        for (int mt = 0; mt < 2; ++mt)
            #pragma unroll
            for (int nt = 0; nt < 2; ++nt) {
                f32x4 c = acc[mt][nt];
                c = __builtin_amdgcn_mfma_f32_16x16x32_bf16(Ah[cur][mt], Bh[cur][nt], c, 0, 0, 0);
                c = __builtin_amdgcn_mfma_f32_16x16x32_bf16(Ah[cur][mt], Bl[cur][nt], c, 0, 0, 0);
                c = __builtin_amdgcn_mfma_f32_16x16x32_bf16(Al[cur][mt], Bh[cur][nt], c, 0, 0, 0);
                acc[mt][nt] = c;
            }
    }

    float* Ob = out + (size_t)b * Cdim * Tdim;
    #pragma unroll
    for (int mt = 0; mt < 2; ++mt) {
        const int m = m32 * 32 + mt * 16 + quad * 4;
        float bb[4];
        #pragma unroll
        for (int r = 0; r < 4; ++r) bb[r] = bo[m + r];
        #pragma unroll
        for (int nt = 0; nt < 2; ++nt) {
            const int t = n32 * 32 + nt * 16 + l15;
            #pragma unroll
            for (int r = 0; r < 4; ++r)
                Ob[(size_t)(m + r) * Tdim + t] = acc[mt][nt][r] + bb[r];
        }
    }
}

// ---------------------------------------------------------------------------
// Barrier-light MFMA flash attention with IN-BLOCK SPLIT-KV:
//  8 waves / block (512 thr). Waves 0-3 process KV tiles 0-7, waves 4-7
//  process tiles 8-15, same Q tile. Final exact online-softmax merge in LDS.
//  -> 16 waves/CU (4/SIMD) instead of 8 (2/SIMD): hides latency that
//  R0-R2 (Occupancy 17%, MfmaUtil 18%) could not.
//  Per-half copies of psh/psl/bandp; shared rk/evs; zero extra HBM traffic.
// ---------------------------------------------------------------------------
__global__ __launch_bounds__(512, 4) void attn_mfma(
    const unsigned short* __restrict__ qhi, const unsigned short* __restrict__ qlo,
    const unsigned short* __restrict__ khi, const unsigned short* __restrict__ klo,
    const unsigned short* __restrict__ vhi, const unsigned short* __restrict__ vlo,
    const float* __restrict__ ek,   // [9,64]
    const float* __restrict__ ev,   // [9,64]
    unsigned short* __restrict__ cxhi, unsigned short* __restrict__ cxlo)
{
    __shared__ alignas(16) unsigned short psh[2][4096], psl[2][4096];
    __shared__ float rk[576];        // rel-k logits (exp2 domain via q scale)
    __shared__ float evs[576];
    __shared__ float bandp[2][576];  // f32 post-exp P band, per half
    __shared__ float mO[4][16][64];  // partner-half Oc for merge
    __shared__ float mML[4][2][64];  // partner-half m_run / l_run

    const int tid = threadIdx.x;
    int it, h, b;
    {
        const int n = blockIdx.x;
        const int xcd = n & 7, slot = n >> 3;
        const int pair = (xcd << 2) | (slot >> 4);
        it = slot & 15;
        b = pair >> 3;
        h = pair & 7;
    }
    const int i0 = it * 64;
    const int lane = tid & 63, w = tid >> 6;    // w: 0..7
    const int s = w >> 2;                       // KV half: 0 or 1
    const int w4 = w & 3;                       // q-row block within tile
    const int l15 = lane & 15, quad = lane >> 4;
    const int m_blk = w4 * 16 + l15;
    const int lo8 = lane << 3;

    unsigned short* pshS = psh[s];
    unsigned short* pslS = psl[s];
    float* bandS = bandp[s];

    const size_t bh16 = (size_t)(b * Hn + h) * 16;

    bf16x8 qfh[2], qfl[2];
    {
        const unsigned short* qth = qhi + ((bh16 + it) << 12);
        const unsigned short* qtl = qlo + ((bh16 + it) << 12);
        #pragma unroll
        for (int ks = 0; ks < 2; ++ks) {
            qfh[ks] = *(const bf16x8*)(qth + (((w4 << 1) | ks) << 9) + lo8);
            qfl[ks] = *(const bf16x8*)(qtl + (((w4 << 1) | ks) << 9) + lo8);
        }
    }

    // rel-k logits: computed once by half 0 (shared rows), read by both halves
    if (s == 0) {
        bf16x8 ekh[2], ekl[2];
        #pragma unroll
        for (int ks = 0; ks < 2; ++ks) {
            #pragma unroll
            for (int j = 0; j < 8; ++j) { ekh[ks][j] = 0; ekl[ks][j] = 0; }
            if (l15 < 9) {
                #pragma unroll
                for (int j = 0; j < 8; ++j) {
                    const float v = ek[l15 * 64 + ks * 32 + quad * 8 + j];
                    const unsigned short hh = f32_bf16_rne(v);
                    ekh[ks][j] = (short)hh;
                    ekl[ks][j] = (short)f32_bf16_rne(v - bf16_f32(hh));
                }
            }
        }
        f32x4 rkD = (f32x4){0.f, 0.f, 0.f, 0.f};
        #pragma unroll
        for (int ks = 0; ks < 2; ++ks) {
            rkD = __builtin_amdgcn_mfma_f32_16x16x32_bf16(qfh[ks], ekh[ks], rkD, 0, 0, 0);
            rkD = __builtin_amdgcn_mfma_f32_16x16x32_bf16(qfh[ks], ekl[ks], rkD, 0, 0, 0);
            rkD = __builtin_amdgcn_mfma_f32_16x16x32_bf16(qfl[ks], ekh[ks], rkD, 0, 0, 0);
        }
        if (l15 < 9) {
            // q is pre-scaled -> rkD already carries QK_SCALE
            #pragma unroll
            for (int r = 0; r < 4; ++r)
                rk[(w4 * 16 + quad * 4 + r) * 9 + l15] = rkD[r];
        }
    }
    for (int idx = tid; idx < 576; idx += 512) evs[idx] = ev[idx];
    __syncthreads();   // rk + evs visible to all 8 waves

    float m_run = -1e30f, l_run = 0.f;
    f32x4 Oc[4];
    #pragma unroll
    for (int ct = 0; ct < 4; ++ct) Oc[ct] = (f32x4){0.f, 0.f, 0.f, 0.f};

    const unsigned short* kh0 = khi + (bh16 << 12);
    const unsigned short* kl0 = klo + (bh16 << 12);
    const unsigned short* vh0 = vhi + (bh16 << 12);
    const unsigned short* vl0 = vlo + (bh16 << 12);

    for (int tt = 0; tt < 8; ++tt) {
        const int t = (s << 3) + tt;
        const int j0 = t << 6;
        const size_t tb = (size_t)t << 12;
        const unsigned short* kht = kh0 + tb;
        const unsigned short* klt = kl0 + tb;
        const unsigned short* vht = vh0 + tb;
        const unsigned short* vlt = vl0 + tb;

        bf16x8 vbh[2][4], vbl[2][4];
        #pragma unroll
        for (int ks = 0; ks < 2; ++ks)
            #pragma unroll
            for (int ct = 0; ct < 4; ++ct) {
                vbh[ks][ct] = *(const bf16x8*)(vht + (((ct << 1) | ks) << 9) + lo8);
                vbl[ks][ct] = *(const bf16x8*)(vlt + (((ct << 1) | ks) << 9) + lo8);
            }

        f32x4 Sc[4];
        #pragma unroll
        for (int jt = 0; jt < 4; ++jt) Sc[jt] = (f32x4){0.f, 0.f, 0.f, 0.f};
        #pragma unroll
        for (int ks = 0; ks < 2; ++ks) {
            bf16x8 ah[4], al[4];
            #pragma unroll
            for (int jt = 0; jt < 4; ++jt) {
                ah[jt] = *(const bf16x8*)(kht + (((jt << 1) | ks) << 9) + lo8);
                al[jt] = *(const bf16x8*)(klt + (((jt << 1) | ks) << 9) + lo8);
            }
            #pragma unroll
            for (int jt = 0; jt < 4; ++jt) {
                Sc[jt] = __builtin_amdgcn_mfma_f32_16x16x32_bf16(ah[jt], qfh[ks], Sc[jt], 0, 0, 0);
                Sc[jt] = __builtin_amdgcn_mfma_f32_16x16x32_bf16(ah[jt], qfl[ks], Sc[jt], 0, 0, 0);
                Sc[jt] = __builtin_amdgcn_mfma_f32_16x16x32_bf16(al[jt], qfh[ks], Sc[jt], 0, 0, 0);
            }
        }

        const int dt = j0 - i0;
        const bool diag = (dt >= -67 && dt <= 67);
        if (diag) {
            #pragma unroll
            for (int jt = 0; jt < 4; ++jt) {
                const int db = dt + jt * 16 + quad * 4 - m_blk;
                #pragma unroll
                for (int r = 0; r < 4; ++r) {
                    const int d = db + r;
                    if ((unsigned)(d + 4) <= 8u) Sc[jt][r] += rk[m_blk * 9 + d + 4];
                }
            }
        }

        // row max (tree)
        const float mt = fmaxf(
            fmaxf(fmaxf(fmaxf(Sc[0][0], Sc[0][1]), fmaxf(Sc[0][2], Sc[0][3])),
                  fmaxf(fmaxf(Sc[1][0], Sc[1][1]), fmaxf(Sc[1][2], Sc[1][3]))),
            fmaxf(fmaxf(fmaxf(Sc[2][0], Sc[2][1]), fmaxf(Sc[2][2], Sc[2][3])),
                  fmaxf(fmaxf(Sc[3][0], Sc[3][1]), fmaxf(Sc[3][2], Sc[3][3]))));
        float mr = fmaxf(mt, __shfl_xor(mt, 16));
        mr = fmaxf(mr, __shfl_xor(mr, 32));
        const float mn = fmaxf(m_run, mr);
        const float alpha = __builtin_amdgcn_exp2f(m_run - mn);

        #pragma unroll
        for (int jt = 0; jt < 4; ++jt)
            #pragma unroll
            for (int r = 0; r < 4; ++r)
                Sc[jt][r] = __builtin_amdgcn_exp2f(Sc[jt][r] - mn);

        float rs = ((Sc[0][0] + Sc[0][1]) + (Sc[0][2] + Sc[0][3]))
                 + ((Sc[1][0] + Sc[1][1]) + (Sc[1][2] + Sc[1][3]))
                 + ((Sc[2][0] + Sc[2][1]) + (Sc[2][2] + Sc[2][3]))
                 + ((Sc[3][0] + Sc[3][1]) + (Sc[3][2] + Sc[3][3]));
        rs += __shfl_xor(rs, 16);
        rs += __shfl_xor(rs, 32);
        l_run = l_run * alpha + rs;
        m_run = mn;

        // f32 band scatter for rel-v (wave-private rows, read after PV)
        if (diag) {
            #pragma unroll
            for (int jt = 0; jt < 4; ++jt) {
                const int db = dt + jt * 16 + quad * 4 - m_blk;
                #pragma unroll
                for (int r = 0; r < 4; ++r) {
                    const int d = db + r;
                    if ((unsigned)(d + 4) <= 8u) bandS[m_blk * 9 + d + 4] = Sc[jt][r];
                }
            }
        }

        #pragma unroll
        for (int jt = 0; jt < 4; ++jt) {
            ushort4 ph, pl;
            ph.x = f32_bf16_rne(Sc[jt][0]); pl.x = f32_bf16_rne(Sc[jt][0] - bf16_f32(ph.x));
            ph.y = f32_bf16_rne(Sc[jt][1]); pl.y = f32_bf16_rne(Sc[jt][1] - bf16_f32(ph.y));
            ph.z = f32_bf16_rne(Sc[jt][2]); pl.z = f32_bf16_rne(Sc[jt][2] - bf16_f32(ph.z));
            ph.w = f32_bf16_rne(Sc[jt][3]); pl.w = f32_bf16_rne(Sc[jt][3] - bf16_f32(ph.w));
            const int o = sw(m_blk, jt * 16 + quad * 4);
            *(ushort4*)&pshS[o] = ph;
            *(ushort4*)&pslS[o] = pl;
        }
        // no barrier: wave reads only its own 16 P rows (per-half copy)

        const float al0 = __shfl(alpha, quad * 4 + 0);
        const float al1 = __shfl(alpha, quad * 4 + 1);
        const float al2 = __shfl(alpha, quad * 4 + 2);
        const float al3 = __shfl(alpha, quad * 4 + 3);
        #pragma unroll
        for (int ct = 0; ct < 4; ++ct) {
            Oc[ct][0] *= al0; Oc[ct][1] *= al1; Oc[ct][2] *= al2; Oc[ct][3] *= al3;
        }
        #pragma unroll
        for (int ks = 0; ks < 2; ++ks) {
            bf16x8 pah = fragld(pshS, m_blk, ks, quad);
            bf16x8 pal = fragld(pslS, m_blk, ks, quad);
            #pragma unroll
            for (int ct = 0; ct < 4; ++ct) {
                Oc[ct] = __builtin_amdgcn_mfma_f32_16x16x32_bf16(pah, vbh[ks][ct], Oc[ct], 0, 0, 0);
                Oc[ct] = __builtin_amdgcn_mfma_f32_16x16x32_bf16(pah, vbl[ks][ct], Oc[ct], 0, 0, 0);
                Oc[ct] = __builtin_amdgcn_mfma_f32_16x16x32_bf16(pal, vbh[ks][ct], Oc[ct], 0, 0, 0);
            }
        }

        if (diag) {
            #pragma unroll
            for (int r = 0; r < 4; ++r) {
                const int mrow = w4 * 16 + quad * 4 + r;
                const int ig = i0 + mrow;
                #pragma unroll
                for (int e = 0; e < 9; ++e) {
                    const int jl = ig + e - 4 - j0;
                    if ((unsigned)jl < 64u) {
                        const float p = bandS[mrow * 9 + e];   // f32 broadcast read
                        #pragma unroll
                        for (int ct = 0; ct < 4; ++ct)
                            Oc[ct][r] += p * evs[e * 64 + ct * 16 + l15];
                    }
                }
            }
        }
    }

    // ---- merge the two KV halves (exact online-softmax combine) ----
    if (s == 1) {
        #pragma unroll
        for (int ct = 0; ct < 4; ++ct)
            #pragma unroll
            for (int r = 0; r < 4; ++r)
                mO[w4][ct * 4 + r][lane] = Oc[ct][r];
        mML[w4][0][lane] = m_run;
        mML[w4][1][lane] = l_run;
    }
    __syncthreads();
    if (s == 1) return;

    const float m1 = mML[w4][0][lane];
    const float l1 = mML[w4][1][lane];
    const float mm = fmaxf(m_run, m1);
    const float a0 = __builtin_amdgcn_exp2f(m_run - mm);
    const float a1 = __builtin_amdgcn_exp2f(m1 - mm);
    const float rlv = 1.f / (l_run * a0 + l1 * a1);

    float a0r[4], a1r[4], rl[4];
    #pragma unroll
    for (int r = 0; r < 4; ++r) {
        a0r[r] = __shfl(a0, quad * 4 + r);
        a1r[r] = __shfl(a1, quad * 4 + r);
        rl[r]  = __shfl(rlv, quad * 4 + r);
    }

    // ---- epilogue: normalize, write ctx B-operand frag-major hi/lo planes ----
    const int ntile16 = it * 4 + w4;
    const int e = l15 & 7;
    #pragma unroll
    for (int ct = 0; ct < 4; ++ct) {
        const int cl = ct * 16 + l15;                    // channel within head
        const int ktc = h * 2 + (cl >> 5);
        const int lane_c = (((ct * 2 + (l15 >> 3)) & 3) << 4) + quad * 4;   // + r
        const size_t base = (((size_t)(b * 64 + ntile16)) * 16 + ktc) * 512;
        #pragma unroll
        for (int r = 0; r < 4; ++r) {
            const float v = (Oc[ct][r] * a0r[r] + mO[w4][ct * 4 + r][lane] * a1r[r]) * rl[r];
            const unsigned short hh = f32_bf16_rne(v);
            const size_t off = base + (size_t)(lane_c + r) * 8 + e;
            cxhi[off] = hh;
            cxlo[off] = f32_bf16_rne(v - bf16_f32(hh));
        }
    }
}

// ---------------------------------------------------------------------------
extern "C" void kernel_launch(void* const* d_in, const int* in_sizes, int n_in,
                              void* d_out, int out_size, void* d_ws, size_t ws_size,
                              hipStream_t stream) {
    const float* x  = (const float*)d_in[0];
    const float* wq = (const float*)d_in[1];
    const float* bq = (const float*)d_in[2];
    const float* wk = (const float*)d_in[3];
    const float* bk = (const float*)d_in[4];
    const float* wv = (const float*)d_in[5];
    const float* bv = (const float*)d_in[6];
    const float* wo = (const float*)d_in[7];
    const float* bo = (const float*)d_in[8];
    const float* ek = (const float*)d_in[9];
    const float* ev = (const float*)d_in[10];
    float* out = (float*)d_out;

    const size_t PW = 2048u * 512u;          // stacked-W plane elements
    const size_t PX = 4u * 1024u * 512u;     // X / ctx / attn plane elements
    unsigned short* WAhi = (unsigned short*)d_ws;
    unsigned short* WAlo = WAhi + PW;
    unsigned short* XBhi = WAlo + PW;
    unsigned short* XBlo = XBhi + PX;
    unsigned short* qhi  = XBlo + PX;
    unsigned short* qlo  = qhi + PX;
    unsigned short* khi  = qlo + PX;
    unsigned short* klo  = khi + PX;
    unsigned short* vhi  = klo + PX;
    unsigned short* vlo  = vhi + PX;
    unsigned short* cxhi = vlo + PX;
    unsigned short* cxlo = cxhi + PX;

    // one-time split/convert of W and X into frag-major planes
    prep_kernel<<<dim3(1536), 256, 0, stream>>>(
        wq, wk, wv, wo, x, WAhi, WAlo, XBhi, XBlo);

    // QKV projection: 768 blocks (3/CU), barrier-free dbuf -> attn planes
    gemm_qkv<<<dim3(768), 256, 0, stream>>>(
        WAhi, WAlo, XBhi, XBlo, bq, bk, bv,
        qhi, qlo, khi, klo, vhi, vlo);

    // split-KV MFMA flash attention: 512 blocks x 8 waves -> ctx planes
    attn_mfma<<<dim3(512), 512, 0, stream>>>(
        qhi, qlo, khi, klo, vhi, vlo, ek, ev, cxhi, cxlo);

    // output projection: 512 blocks (2/CU), A=Wo, B=ctx -> natural fp32 out
    gemm_out<<<dim3(512), 256, 0, stream>>>(
        WAhi, WAlo, cxhi, cxlo, bo, out);
}

// Round 4
// 191.825 us; speedup vs baseline: 1.1256x; 1.1256x over previous
//
#include <hip/hip_runtime.h>
#include <hip/hip_bf16.h>

// Problem constants (B, C, T, H, KC, WIN) = (4, 512, 1024, 8, 64, 4)
#define Bdim 4
#define Cdim 512
#define Tdim 1024
#define Hn   8
#define KCd  64

// softmax scale folded into q: 1/sqrt(KC) * log2(e) -> scores in exp2 domain
#define QK_SCALE 0.18033688011112042f

typedef __attribute__((ext_vector_type(8))) short bf16x8;   // 8 bf16 = 4 VGPR
typedef __attribute__((ext_vector_type(4))) float f32x4;    // MFMA C/D

__device__ __forceinline__ unsigned short f32_bf16_rne(float f) {
    unsigned u = __float_as_uint(f);
    u += 0x7FFFu + ((u >> 16) & 1u);
    return (unsigned short)(u >> 16);
}
__device__ __forceinline__ float bf16_f32(unsigned short h) {
    return __uint_as_float(((unsigned)h) << 16);
}
__device__ __forceinline__ void split8(const float* f, bf16x8& h8, bf16x8& l8) {
    #pragma unroll
    for (int e = 0; e < 8; ++e) {
        const unsigned short hh = f32_bf16_rne(f[e]);
        h8[e] = (short)hh;
        l8[e] = (short)f32_bf16_rne(f[e] - bf16_f32(hh));
    }
}

// LDS 64x64 tile XOR swizzle (only attention's P round-trip)
__device__ __forceinline__ int sw(int row, int col) {
    return (row << 6) + ((((col >> 3) ^ (row & 7)) << 3) | (col & 7));
}
__device__ __forceinline__ bf16x8 fragld(const unsigned short* a, int row, int kstep, int quad) {
    return *(const bf16x8*)&a[(row << 6) + ((((kstep << 2) | quad) ^ (row & 7)) << 3)];
}

// ---------------------------------------------------------------------------
// FRAG-MAJOR plane layouts (hi/lo pre-split), as validated in R8/R9:
//  A-plane (stacked [wq;wk;wv;wo], 2048 rows x 512 k):
//    [mtile16:128][kt:16][lane:64][e:8]; elem(m,k): lane=((k>>3)&3)*16+(m&15), e=k&7
//  B-plane (X / ctx, per batch n=1024, k=512):
//    [b*64+ntile16][kt:16][lane:64][e:8]; elem(n,k): lane=((k>>3)&3)*16+(n&15), e=k&7
//  Attn planes per (b,h), 16 time-tiles of 64x64:
//    row-type (Q,K): g=(t>>4)*2+(c>>5), lane=((c>>3)&3)*16+(t&15), e=c&7
//    col-type (V):   g=(c>>4)*2+(t>>5), lane=((t>>3)&3)*16+(c&15), e=t&7
// ---------------------------------------------------------------------------

// prep: one-time fp32 -> hi/lo split into A/B planes (R9, measured good)
__global__ __launch_bounds__(256) void prep_kernel(
    const float* __restrict__ wq, const float* __restrict__ wk,
    const float* __restrict__ wv, const float* __restrict__ wo,
    const float* __restrict__ x,
    unsigned short* __restrict__ WAhi, unsigned short* __restrict__ WAlo,
    unsigned short* __restrict__ XBhi, unsigned short* __restrict__ XBlo)
{
    const int w = threadIdx.x >> 6, lane = threadIdx.x & 63;
    const int l15 = lane & 15, quad = lane >> 4;
    const int task = blockIdx.x * 4 + w;

    if (task < 2048) {
        const int mtile = task >> 4, kt = task & 15;
        const int sel = mtile >> 5;
        const float* W = sel == 0 ? wq : (sel == 1 ? wk : (sel == 2 ? wv : wo));
        const int row = (mtile & 31) * 16 + l15;
        const float* p = W + (size_t)row * Cdim + kt * 32 + quad * 8;
        float f[8];
        *(float4*)&f[0] = *(const float4*)p;
        *(float4*)&f[4] = *(const float4*)(p + 4);
        bf16x8 h8, l8;
        split8(f, h8, l8);
        const size_t base = (size_t)task * 512 + lane * 8;
        *(bf16x8*)(WAhi + base) = h8;
        *(bf16x8*)(WAlo + base) = l8;
    } else {
        const int t2 = task - 2048;
        const int b = t2 >> 10, ntile = (t2 >> 4) & 63, kt = t2 & 15;
        const float* Xb = x + (size_t)b * Cdim * Tdim;
        const int n = ntile * 16 + l15;
        const int k0 = kt * 32 + quad * 8;
        float f[8];
        #pragma unroll
        for (int e = 0; e < 8; ++e) f[e] = Xb[(size_t)(k0 + e) * Tdim + n];
        bf16x8 h8, l8;
        split8(f, h8, l8);
        const size_t base = (size_t)t2 * 512 + lane * 8;
        *(bf16x8*)(XBhi + base) = h8;
        *(bf16x8*)(XBlo + base) = l8;
    }
}

// ---------------------------------------------------------------------------
// QKV GEMM: barrier-free, zero-LDS, dbuf. Wave = 64m x 32n x 512k.
// 3072 wave-jobs -> 768 blocks = 3 blocks/CU (12 waves/CU).
// XCD-clustered: 16 (b,n32) columns per XCD share B stripes in that L2.
// q rows are pre-scaled by QK_SCALE so attention scores land in exp2 domain.
// ---------------------------------------------------------------------------
__global__ __launch_bounds__(256, 3) void gemm_qkv(
    const unsigned short* __restrict__ Ahi, const unsigned short* __restrict__ Alo,
    const unsigned short* __restrict__ Bhi, const unsigned short* __restrict__ Blo,
    const float* __restrict__ bq, const float* __restrict__ bk, const float* __restrict__ bv,
    unsigned short* __restrict__ qhi, unsigned short* __restrict__ qlo,
    unsigned short* __restrict__ khi, unsigned short* __restrict__ klo,
    unsigned short* __restrict__ vhi, unsigned short* __restrict__ vlo)
{
    const int tid = threadIdx.x;
    const int w = tid >> 6, lane = tid & 63;
    const int l15 = lane & 15, quad = lane >> 4;
    const int lo8 = lane << 3;

    const int id = blockIdx.x;
    const int xcd = id & 7, slot = id >> 3;     // slot 0..95
    const int col = xcd * 16 + slot / 6;        // 0..127 = (b, n32)
    const int mg  = slot % 6;
    const int b = col >> 5, n32 = col & 31;
    const int m64 = mg * 4 + w;                 // 0..23 stacked q/k/v
    const int sel = m64 >> 3;
    const int mtb = m64 * 4;                    // mtile16 base (q:0-31 k:32-63 v:64-95)
    const int ntb = b * 64 + n32 * 2;

    f32x4 acc[4][2];
    #pragma unroll
    for (int i = 0; i < 4; ++i)
        #pragma unroll
        for (int j = 0; j < 2; ++j) acc[i][j] = (f32x4){0.f, 0.f, 0.f, 0.f};

    bf16x8 Ah[2][4], Al[2][4], Bh[2][2], Bl[2][2];
    #pragma unroll
    for (int mt = 0; mt < 4; ++mt) {
        const size_t o = (size_t)(mtb + mt) * 8192 + lo8;
        Ah[0][mt] = *(const bf16x8*)(Ahi + o);
        Al[0][mt] = *(const bf16x8*)(Alo + o);
    }
    #pragma unroll
    for (int nt = 0; nt < 2; ++nt) {
        const size_t o = (size_t)(ntb + nt) * 8192 + lo8;
        Bh[0][nt] = *(const bf16x8*)(Bhi + o);
        Bl[0][nt] = *(const bf16x8*)(Blo + o);
    }

    for (int kt = 0; kt < 16; ++kt) {
        const int cur = kt & 1, nxt = cur ^ 1;
        if (kt < 15) {
            const int kn = (kt + 1) * 512;
            #pragma unroll
            for (int mt = 0; mt < 4; ++mt) {
                const size_t o = (size_t)(mtb + mt) * 8192 + kn + lo8;
                Ah[nxt][mt] = *(const bf16x8*)(Ahi + o);
                Al[nxt][mt] = *(const bf16x8*)(Alo + o);
            }
            #pragma unroll
            for (int nt = 0; nt < 2; ++nt) {
                const size_t o = (size_t)(ntb + nt) * 8192 + kn + lo8;
                Bh[nxt][nt] = *(const bf16x8*)(Bhi + o);
                Bl[nxt][nt] = *(const bf16x8*)(Blo + o);
            }
        }
        #pragma unroll
        for (int mt = 0; mt < 4; ++mt)
            #pragma unroll
            for (int nt = 0; nt < 2; ++nt) {
                f32x4 c = acc[mt][nt];
                c = __builtin_amdgcn_mfma_f32_16x16x32_bf16(Ah[cur][mt], Bh[cur][nt], c, 0, 0, 0);
                c = __builtin_amdgcn_mfma_f32_16x16x32_bf16(Ah[cur][mt], Bl[cur][nt], c, 0, 0, 0);
                c = __builtin_amdgcn_mfma_f32_16x16x32_bf16(Al[cur][mt], Bh[cur][nt], c, 0, 0, 0);
                acc[mt][nt] = c;
            }
    }

    // ---- epilogue: D[m=quad*4+r (channel)][n=l15 (time)] -> attn planes ----
    const int head = m64 & 7;
    const size_t hbase = ((size_t)(b * Hn + head) * 16) << 12;
    if (sel < 2) {
        const float* Bv = sel == 0 ? bq : bk;
        unsigned short* ph = sel == 0 ? qhi : khi;
        unsigned short* pl = sel == 0 ? qlo : klo;
        const float qscale = sel == 0 ? QK_SCALE : 1.0f;
        #pragma unroll
        for (int mt = 0; mt < 4; ++mt) {
            const int c0 = mt * 16 + quad * 4;          // channel-in-head base
            float bb[4];
            #pragma unroll
            for (int r = 0; r < 4; ++r) bb[r] = Bv[head * 64 + c0 + r];
            const int lane_out = (((c0 >> 3) & 3) << 4) + l15;
            const int e0 = c0 & 7;                      // 0 or 4
            const int cg = c0 >> 5;
            #pragma unroll
            for (int nt = 0; nt < 2; ++nt) {
                const int tile = n32 >> 1;
                const int rhi = (n32 & 1) * 2 + nt;     // (t&63)>>4
                const int g = rhi * 2 + cg;
                const size_t off = hbase + ((size_t)tile << 12) + g * 512
                                 + (size_t)lane_out * 8 + e0;
                ushort4 h4, l4;
                #pragma unroll
                for (int r = 0; r < 4; ++r) {
                    const float v = (acc[mt][nt][r] + bb[r]) * qscale;
                    const unsigned short hh = f32_bf16_rne(v);
                    ((unsigned short*)&h4)[r] = hh;
                    ((unsigned short*)&l4)[r] = f32_bf16_rne(v - bf16_f32(hh));
                }
                *(ushort4*)(ph + off) = h4;
                *(ushort4*)(pl + off) = l4;
            }
        }
    } else {
        #pragma unroll
        for (int mt = 0; mt < 4; ++mt) {
            const int c0 = mt * 16 + quad * 4;
            float bb[4];
            #pragma unroll
            for (int r = 0; r < 4; ++r) bb[r] = bv[head * 64 + c0 + r];
            #pragma unroll
            for (int nt = 0; nt < 2; ++nt) {
                const int t = n32 * 32 + nt * 16 + l15;
                const int tile = t >> 6, jl = t & 63;
                const int jg = jl >> 5, lanej = ((jl >> 3) & 3) << 4;
                const int e = jl & 7;
                const size_t tb = hbase + ((size_t)tile << 12);
                #pragma unroll
                for (int r = 0; r < 4; ++r) {
                    const int c = c0 + r;
                    const int g = mt * 2 + jg;          // c>>4 == mt here
                    const int lane_v = lanej + (c & 15);
                    const float v = acc[mt][nt][r] + bb[r];
                    const unsigned short hh = f32_bf16_rne(v);
                    const size_t off = tb + g * 512 + (size_t)lane_v * 8 + e;
                    vhi[off] = hh;
                    vlo[off] = f32_bf16_rne(v - bf16_f32(hh));
                }
            }
        }
    }
}

// ---------------------------------------------------------------------------
// Out-projection GEMM: barrier-free, zero-LDS, dbuf. Wave = 32m x 32n x 512k.
// 2048 wave-jobs -> 512 blocks = 2 blocks/CU (every CU active).
// A = Wo rows (mtile16 96..127), B = ctx planes from attention.
// ---------------------------------------------------------------------------
__global__ __launch_bounds__(256) void gemm_out(
    const unsigned short* __restrict__ Ahi, const unsigned short* __restrict__ Alo,
    const unsigned short* __restrict__ Bhi, const unsigned short* __restrict__ Blo,
    const float* __restrict__ bo, float* __restrict__ out)
{
    const int tid = threadIdx.x;
    const int w = tid >> 6, lane = tid & 63;
    const int l15 = lane & 15, quad = lane >> 4;
    const int lo8 = lane << 3;

    const int id = blockIdx.x;
    const int xcd = id & 7, slot = id >> 3;     // slot 0..63
    const int col = xcd * 16 + (slot >> 2);     // 0..127 = (b, n32)
    const int mg  = slot & 3;
    const int b = col >> 5, n32 = col & 31;
    const int m32 = mg * 4 + w;                 // 0..15
    const int mtb = 96 + m32 * 2;               // Wo mtile16 base
    const int ntb = b * 64 + n32 * 2;

    f32x4 acc[2][2];
    #pragma unroll
    for (int i = 0; i < 2; ++i)
        #pragma unroll
        for (int j = 0; j < 2; ++j) acc[i][j] = (f32x4){0.f, 0.f, 0.f, 0.f};

    bf16x8 Ah[2][2], Al[2][2], Bh[2][2], Bl[2][2];
    #pragma unroll
    for (int mt = 0; mt < 2; ++mt) {
        const size_t o = (size_t)(mtb + mt) * 8192 + lo8;
        Ah[0][mt] = *(const bf16x8*)(Ahi + o);
        Al[0][mt] = *(const bf16x8*)(Alo + o);
    }
    #pragma unroll
    for (int nt = 0; nt < 2; ++nt) {
        const size_t o = (size_t)(ntb + nt) * 8192 + lo8;
        Bh[0][nt] = *(const bf16x8*)(Bhi + o);
        Bl[0][nt] = *(const bf16x8*)(Blo + o);
    }

    for (int kt = 0; kt < 16; ++kt) {
        const int cur = kt & 1, nxt = cur ^ 1;
        if (kt < 15) {
            const int kn = (kt + 1) * 512;
            #pragma unroll
            for (int mt = 0; mt < 2; ++mt) {
                const size_t o = (size_t)(mtb + mt) * 8192 + kn + lo8;
                Ah[nxt][mt] = *(const bf16x8*)(Ahi + o);
                Al[nxt][mt] = *(const bf16x8*)(Alo + o);
            }
            #pragma unroll
            for (int nt = 0; nt < 2; ++nt) {
                const size_t o = (size_t)(ntb + nt) * 8192 + kn + lo8;
                Bh[nxt][nt] = *(const bf16x8*)(Bhi + o);
                Bl[nxt][nt] = *(const bf16x8*)(Blo + o);
            }
        }
        #pragma unroll
        for (int mt = 0; mt < 2; ++mt)
            #pragma unroll
            for (int nt = 0; nt < 2; ++nt) {
                f32x4 c = acc[mt][nt];
                c = __builtin_amdgcn_mfma_f32_16x16x32_bf16(Ah[cur][mt], Bh[cur][nt], c, 0, 0, 0);
                c = __builtin_amdgcn_mfma_f32_16x16x32_bf16(Ah[cur][mt], Bl[cur][nt], c, 0, 0, 0);
                c = __builtin_amdgcn_mfma_f32_16x16x32_bf16(Al[cur][mt], Bh[cur][nt], c, 0, 0, 0);
                acc[mt][nt] = c;
            }
    }

    float* Ob = out + (size_t)b * Cdim * Tdim;
    #pragma unroll
    for (int mt = 0; mt < 2; ++mt) {
        const int m = m32 * 32 + mt * 16 + quad * 4;
        float bb[4];
        #pragma unroll
        for (int r = 0; r < 4; ++r) bb[r] = bo[m + r];
        #pragma unroll
        for (int nt = 0; nt < 2; ++nt) {
            const int t = n32 * 32 + nt * 16 + l15;
            #pragma unroll
            for (int r = 0; r < 4; ++r)
                Ob[(size_t)(m + r) * Tdim + t] = acc[mt][nt][r] + bb[r];
        }
    }
}

// ---------------------------------------------------------------------------
// Barrier-light MFMA flash attention with IN-BLOCK SPLIT-KV (R3 structure).
// R4 fix: __launch_bounds__(512) with NO min-waves clause. R3's (512,4)
// capped VGPR at 64 -> massive scratch spills (FETCH 71MB, WRITE 44MB).
// At natural ~100-128 VGPR: no spills, LDS (60.4KB) gives 2 blocks/CU
// = 16 waves/CU = 4 waves/SIMD, double R2's occupancy.
// ---------------------------------------------------------------------------
__global__ __launch_bounds__(512) void attn_mfma(
    const unsigned short* __restrict__ qhi, const unsigned short* __restrict__ qlo,
    const unsigned short* __restrict__ khi, const unsigned short* __restrict__ klo,
    const unsigned short* __restrict__ vhi, const unsigned short* __restrict__ vlo,
    const float* __restrict__ ek,   // [9,64]
    const float* __restrict__ ev,   // [9,64]
    unsigned short* __restrict__ cxhi, unsigned short* __restrict__ cxlo)
{
    __shared__ alignas(16) unsigned short psh[2][4096], psl[2][4096];
    __shared__ float rk[576];        // rel-k logits (exp2 domain via q scale)
    __shared__ float evs[576];
    __shared__ float bandp[2][576];  // f32 post-exp P band, per half
    __shared__ float mO[4][16][64];  // partner-half Oc for merge
    __shared__ float mML[4][2][64];  // partner-half m_run / l_run

    const int tid = threadIdx.x;
    int it, h, b;
    {
        const int n = blockIdx.x;
        const int xcd = n & 7, slot = n >> 3;
        const int pair = (xcd << 2) | (slot >> 4);
        it = slot & 15;
        b = pair >> 3;
        h = pair & 7;
    }
    const int i0 = it * 64;
    const int lane = tid & 63, w = tid >> 6;    // w: 0..7
    const int s = w >> 2;                       // KV half: 0 or 1
    const int w4 = w & 3;                       // q-row block within tile
    const int l15 = lane & 15, quad = lane >> 4;
    const int m_blk = w4 * 16 + l15;
    const int lo8 = lane << 3;

    unsigned short* pshS = psh[s];
    unsigned short* pslS = psl[s];
    float* bandS = bandp[s];

    const size_t bh16 = (size_t)(b * Hn + h) * 16;

    bf16x8 qfh[2], qfl[2];
    {
        const unsigned short* qth = qhi + ((bh16 + it) << 12);
        const unsigned short* qtl = qlo + ((bh16 + it) << 12);
        #pragma unroll
        for (int ks = 0; ks < 2; ++ks) {
            qfh[ks] = *(const bf16x8*)(qth + (((w4 << 1) | ks) << 9) + lo8);
            qfl[ks] = *(const bf16x8*)(qtl + (((w4 << 1) | ks) << 9) + lo8);
        }
    }

    // rel-k logits: computed once by half 0 (shared rows), read by both halves
    if (s == 0) {
        bf16x8 ekh[2], ekl[2];
        #pragma unroll
        for (int ks = 0; ks < 2; ++ks) {
            #pragma unroll
            for (int j = 0; j < 8; ++j) { ekh[ks][j] = 0; ekl[ks][j] = 0; }
            if (l15 < 9) {
                #pragma unroll
                for (int j = 0; j < 8; ++j) {
                    const float v = ek[l15 * 64 + ks * 32 + quad * 8 + j];
                    const unsigned short hh = f32_bf16_rne(v);
                    ekh[ks][j] = (short)hh;
                    ekl[ks][j] = (short)f32_bf16_rne(v - bf16_f32(hh));
                }
            }
        }
        f32x4 rkD = (f32x4){0.f, 0.f, 0.f, 0.f};
        #pragma unroll
        for (int ks = 0; ks < 2; ++ks) {
            rkD = __builtin_amdgcn_mfma_f32_16x16x32_bf16(qfh[ks], ekh[ks], rkD, 0, 0, 0);
            rkD = __builtin_amdgcn_mfma_f32_16x16x32_bf16(qfh[ks], ekl[ks], rkD, 0, 0, 0);
            rkD = __builtin_amdgcn_mfma_f32_16x16x32_bf16(qfl[ks], ekh[ks], rkD, 0, 0, 0);
        }
        if (l15 < 9) {
            // q is pre-scaled -> rkD already carries QK_SCALE
            #pragma unroll
            for (int r = 0; r < 4; ++r)
                rk[(w4 * 16 + quad * 4 + r) * 9 + l15] = rkD[r];
        }
    }
    for (int idx = tid; idx < 576; idx += 512) evs[idx] = ev[idx];
    __syncthreads();   // rk + evs visible to all 8 waves

    float m_run = -1e30f, l_run = 0.f;
    f32x4 Oc[4];
    #pragma unroll
    for (int ct = 0; ct < 4; ++ct) Oc[ct] = (f32x4){0.f, 0.f, 0.f, 0.f};

    const unsigned short* kh0 = khi + (bh16 << 12);
    const unsigned short* kl0 = klo + (bh16 << 12);
    const unsigned short* vh0 = vhi + (bh16 << 12);
    const unsigned short* vl0 = vlo + (bh16 << 12);

    for (int tt = 0; tt < 8; ++tt) {
        const int t = (s << 3) + tt;
        const int j0 = t << 6;
        const size_t tb = (size_t)t << 12;
        const unsigned short* kht = kh0 + tb;
        const unsigned short* klt = kl0 + tb;
        const unsigned short* vht = vh0 + tb;
        const unsigned short* vlt = vl0 + tb;

        bf16x8 vbh[2][4], vbl[2][4];
        #pragma unroll
        for (int ks = 0; ks < 2; ++ks)
            #pragma unroll
            for (int ct = 0; ct < 4; ++ct) {
                vbh[ks][ct] = *(const bf16x8*)(vht + (((ct << 1) | ks) << 9) + lo8);
                vbl[ks][ct] = *(const bf16x8*)(vlt + (((ct << 1) | ks) << 9) + lo8);
            }

        f32x4 Sc[4];
        #pragma unroll
        for (int jt = 0; jt < 4; ++jt) Sc[jt] = (f32x4){0.f, 0.f, 0.f, 0.f};
        #pragma unroll
        for (int ks = 0; ks < 2; ++ks) {
            bf16x8 ah[4], al[4];
            #pragma unroll
            for (int jt = 0; jt < 4; ++jt) {
                ah[jt] = *(const bf16x8*)(kht + (((jt << 1) | ks) << 9) + lo8);
                al[jt] = *(const bf16x8*)(klt + (((jt << 1) | ks) << 9) + lo8);
            }
            #pragma unroll
            for (int jt = 0; jt < 4; ++jt) {
                Sc[jt] = __builtin_amdgcn_mfma_f32_16x16x32_bf16(ah[jt], qfh[ks], Sc[jt], 0, 0, 0);
                Sc[jt] = __builtin_amdgcn_mfma_f32_16x16x32_bf16(ah[jt], qfl[ks], Sc[jt], 0, 0, 0);
                Sc[jt] = __builtin_amdgcn_mfma_f32_16x16x32_bf16(al[jt], qfh[ks], Sc[jt], 0, 0, 0);
            }
        }

        const int dt = j0 - i0;
        const bool diag = (dt >= -67 && dt <= 67);
        if (diag) {
            #pragma unroll
            for (int jt = 0; jt < 4; ++jt) {
                const int db = dt + jt * 16 + quad * 4 - m_blk;
                #pragma unroll
                for (int r = 0; r < 4; ++r) {
                    const int d = db + r;
                    if ((unsigned)(d + 4) <= 8u) Sc[jt][r] += rk[m_blk * 9 + d + 4];
                }
            }
        }

        // row max (tree)
        const float mt = fmaxf(
            fmaxf(fmaxf(fmaxf(Sc[0][0], Sc[0][1]), fmaxf(Sc[0][2], Sc[0][3])),
                  fmaxf(fmaxf(Sc[1][0], Sc[1][1]), fmaxf(Sc[1][2], Sc[1][3]))),
            fmaxf(fmaxf(fmaxf(Sc[2][0], Sc[2][1]), fmaxf(Sc[2][2], Sc[2][3])),
                  fmaxf(fmaxf(Sc[3][0], Sc[3][1]), fmaxf(Sc[3][2], Sc[3][3]))));
        float mr = fmaxf(mt, __shfl_xor(mt, 16));
        mr = fmaxf(mr, __shfl_xor(mr, 32));
        const float mn = fmaxf(m_run, mr);
        const float alpha = __builtin_amdgcn_exp2f(m_run - mn);

        #pragma unroll
        for (int jt = 0; jt < 4; ++jt)
            #pragma unroll
            for (int r = 0; r < 4; ++r)
                Sc[jt][r] = __builtin_amdgcn_exp2f(Sc[jt][r] - mn);

        float rs = ((Sc[0][0] + Sc[0][1]) + (Sc[0][2] + Sc[0][3]))
                 + ((Sc[1][0] + Sc[1][1]) + (Sc[1][2] + Sc[1][3]))
                 + ((Sc[2][0] + Sc[2][1]) + (Sc[2][2] + Sc[2][3]))
                 + ((Sc[3][0] + Sc[3][1]) + (Sc[3][2] + Sc[3][3]));
        rs += __shfl_xor(rs, 16);
        rs += __shfl_xor(rs, 32);
        l_run = l_run * alpha + rs;
        m_run = mn;

        // f32 band scatter for rel-v (wave-private rows, read after PV)
        if (diag) {
            #pragma unroll
            for (int jt = 0; jt < 4; ++jt) {
                const int db = dt + jt * 16 + quad * 4 - m_blk;
                #pragma unroll
                for (int r = 0; r < 4; ++r) {
                    const int d = db + r;
                    if ((unsigned)(d + 4) <= 8u) bandS[m_blk * 9 + d + 4] = Sc[jt][r];
                }
            }
        }

        #pragma unroll
        for (int jt = 0; jt < 4; ++jt) {
            ushort4 ph, pl;
            ph.x = f32_bf16_rne(Sc[jt][0]); pl.x = f32_bf16_rne(Sc[jt][0] - bf16_f32(ph.x));
            ph.y = f32_bf16_rne(Sc[jt][1]); pl.y = f32_bf16_rne(Sc[jt][1] - bf16_f32(ph.y));
            ph.z = f32_bf16_rne(Sc[jt][2]); pl.z = f32_bf16_rne(Sc[jt][2] - bf16_f32(ph.z));
            ph.w = f32_bf16_rne(Sc[jt][3]); pl.w = f32_bf16_rne(Sc[jt][3] - bf16_f32(ph.w));
            const int o = sw(m_blk, jt * 16 + quad * 4);
            *(ushort4*)&pshS[o] = ph;
            *(ushort4*)&pslS[o] = pl;
        }
        // no barrier: wave reads only its own 16 P rows (per-half copy)

        const float al0 = __shfl(alpha, quad * 4 + 0);
        const float al1 = __shfl(alpha, quad * 4 + 1);
        const float al2 = __shfl(alpha, quad * 4 + 2);
        const float al3 = __shfl(alpha, quad * 4 + 3);
        #pragma unroll
        for (int ct = 0; ct < 4; ++ct) {
            Oc[ct][0] *= al0; Oc[ct][1] *= al1; Oc[ct][2] *= al2; Oc[ct][3] *= al3;
        }
        #pragma unroll
        for (int ks = 0; ks < 2; ++ks) {
            bf16x8 pah = fragld(pshS, m_blk, ks, quad);
            bf16x8 pal = fragld(pslS, m_blk, ks, quad);
            #pragma unroll
            for (int ct = 0; ct < 4; ++ct) {
                Oc[ct] = __builtin_amdgcn_mfma_f32_16x16x32_bf16(pah, vbh[ks][ct], Oc[ct], 0, 0, 0);
                Oc[ct] = __builtin_amdgcn_mfma_f32_16x16x32_bf16(pah, vbl[ks][ct], Oc[ct], 0, 0, 0);
                Oc[ct] = __builtin_amdgcn_mfma_f32_16x16x32_bf16(pal, vbh[ks][ct], Oc[ct], 0, 0, 0);
            }
        }

        if (diag) {
            #pragma unroll
            for (int r = 0; r < 4; ++r) {
                const int mrow = w4 * 16 + quad * 4 + r;
                const int ig = i0 + mrow;
                #pragma unroll
                for (int e = 0; e < 9; ++e) {
                    const int jl = ig + e - 4 - j0;
                    if ((unsigned)jl < 64u) {
                        const float p = bandS[mrow * 9 + e];   // f32 broadcast read
                        #pragma unroll
                        for (int ct = 0; ct < 4; ++ct)
                            Oc[ct][r] += p * evs[e * 64 + ct * 16 + l15];
                    }
                }
            }
        }
    }

    // ---- merge the two KV halves (exact online-softmax combine) ----
    if (s == 1) {
        #pragma unroll
        for (int ct = 0; ct < 4; ++ct)
            #pragma unroll
            for (int r = 0; r < 4; ++r)
                mO[w4][ct * 4 + r][lane] = Oc[ct][r];
        mML[w4][0][lane] = m_run;
        mML[w4][1][lane] = l_run;
    }
    __syncthreads();
    if (s == 1) return;

    const float m1 = mML[w4][0][lane];
    const float l1 = mML[w4][1][lane];
    const float mm = fmaxf(m_run, m1);
    const float a0 = __builtin_amdgcn_exp2f(m_run - mm);
    const float a1 = __builtin_amdgcn_exp2f(m1 - mm);
    const float rlv = 1.f / (l_run * a0 + l1 * a1);

    float a0r[4], a1r[4], rl[4];
    #pragma unroll
    for (int r = 0; r < 4; ++r) {
        a0r[r] = __shfl(a0, quad * 4 + r);
        a1r[r] = __shfl(a1, quad * 4 + r);
        rl[r]  = __shfl(rlv, quad * 4 + r);
    }

    // ---- epilogue: normalize, write ctx B-operand frag-major hi/lo planes ----
    const int ntile16 = it * 4 + w4;
    const int e = l15 & 7;
    #pragma unroll
    for (int ct = 0; ct < 4; ++ct) {
        const int cl = ct * 16 + l15;                    // channel within head
        const int ktc = h * 2 + (cl >> 5);
        const int lane_c = (((ct * 2 + (l15 >> 3)) & 3) << 4) + quad * 4;   // + r
        const size_t base = (((size_t)(b * 64 + ntile16)) * 16 + ktc) * 512;
        #pragma unroll
        for (int r = 0; r < 4; ++r) {
            const float v = (Oc[ct][r] * a0r[r] + mO[w4][ct * 4 + r][lane] * a1r[r]) * rl[r];
            const unsigned short hh = f32_bf16_rne(v);
            const size_t off = base + (size_t)(lane_c + r) * 8 + e;
            cxhi[off] = hh;
            cxlo[off] = f32_bf16_rne(v - bf16_f32(hh));
        }
    }
}

// ---------------------------------------------------------------------------
extern "C" void kernel_launch(void* const* d_in, const int* in_sizes, int n_in,
                              void* d_out, int out_size, void* d_ws, size_t ws_size,
                              hipStream_t stream) {
    const float* x  = (const float*)d_in[0];
    const float* wq = (const float*)d_in[1];
    const float* bq = (const float*)d_in[2];
    const float* wk = (const float*)d_in[3];
    const float* bk = (const float*)d_in[4];
    const float* wv = (const float*)d_in[5];
    const float* bv = (const float*)d_in[6];
    const float* wo = (const float*)d_in[7];
    const float* bo = (const float*)d_in[8];
    const float* ek = (const float*)d_in[9];
    const float* ev = (const float*)d_in[10];
    float* out = (float*)d_out;

    const size_t PW = 2048u * 512u;          // stacked-W plane elements
    const size_t PX = 4u * 1024u * 512u;     // X / ctx / attn plane elements
    unsigned short* WAhi = (unsigned short*)d_ws;
    unsigned short* WAlo = WAhi + PW;
    unsigned short* XBhi = WAlo + PW;
    unsigned short* XBlo = XBhi + PX;
    unsigned short* qhi  = XBlo + PX;
    unsigned short* qlo  = qhi + PX;
    unsigned short* khi  = qlo + PX;
    unsigned short* klo  = khi + PX;
    unsigned short* vhi  = klo + PX;
    unsigned short* vlo  = vhi + PX;
    unsigned short* cxhi = vlo + PX;
    unsigned short* cxlo = cxhi + PX;

    // one-time split/convert of W and X into frag-major planes
    prep_kernel<<<dim3(1536), 256, 0, stream>>>(
        wq, wk, wv, wo, x, WAhi, WAlo, XBhi, XBlo);

    // QKV projection: 768 blocks (3/CU), barrier-free dbuf -> attn planes
    gemm_qkv<<<dim3(768), 256, 0, stream>>>(
        WAhi, WAlo, XBhi, XBlo, bq, bk, bv,
        qhi, qlo, khi, klo, vhi, vlo);

    // split-KV MFMA flash attention: 512 blocks x 8 waves -> ctx planes
    attn_mfma<<<dim3(512), 512, 0, stream>>>(
        qhi, qlo, khi, klo, vhi, vlo, ek, ev, cxhi, cxlo);

    // output projection: 512 blocks (2/CU), A=Wo, B=ctx -> natural fp32 out
    gemm_out<<<dim3(512), 256, 0, stream>>>(
        WAhi, WAlo, cxhi, cxlo, bo, out);
}

// Round 5
// 191.767 us; speedup vs baseline: 1.1260x; 1.0003x over previous
//
#include <hip/hip_runtime.h>
#include <hip/hip_bf16.h>

// Problem constants (B, C, T, H, KC, WIN) = (4, 512, 1024, 8, 64, 4)
#define Bdim 4
#define Cdim 512
#define Tdim 1024
#define Hn   8
#define KCd  64

// softmax scale folded into q: 1/sqrt(KC) * log2(e) -> scores in exp2 domain
#define QK_SCALE 0.18033688011112042f

typedef __attribute__((ext_vector_type(8))) short bf16x8;   // 8 bf16 = 4 VGPR
typedef __attribute__((ext_vector_type(4))) float f32x4;    // MFMA C/D

__device__ __forceinline__ unsigned short f32_bf16_rne(float f) {
    unsigned u = __float_as_uint(f);
    u += 0x7FFFu + ((u >> 16) & 1u);
    return (unsigned short)(u >> 16);
}
__device__ __forceinline__ float bf16_f32(unsigned short h) {
    return __uint_as_float(((unsigned)h) << 16);
}
__device__ __forceinline__ void split8(const float* f, bf16x8& h8, bf16x8& l8) {
    #pragma unroll
    for (int e = 0; e < 8; ++e) {
        const unsigned short hh = f32_bf16_rne(f[e]);
        h8[e] = (short)hh;
        l8[e] = (short)f32_bf16_rne(f[e] - bf16_f32(hh));
    }
}

// LDS 64x64 tile XOR swizzle (only attention's P round-trip)
__device__ __forceinline__ int sw(int row, int col) {
    return (row << 6) + ((((col >> 3) ^ (row & 7)) << 3) | (col & 7));
}
__device__ __forceinline__ bf16x8 fragld(const unsigned short* a, int row, int kstep, int quad) {
    return *(const bf16x8*)&a[(row << 6) + ((((kstep << 2) | quad) ^ (row & 7)) << 3)];
}

// ---------------------------------------------------------------------------
// FRAG-MAJOR plane layouts (hi/lo pre-split), as validated in R8/R9:
//  A-plane (stacked [wq;wk;wv;wo], 2048 rows x 512 k):
//    [mtile16:128][kt:16][lane:64][e:8]; elem(m,k): lane=((k>>3)&3)*16+(m&15), e=k&7
//  B-plane (X / ctx, per batch n=1024, k=512):
//    [b*64+ntile16][kt:16][lane:64][e:8]; elem(n,k): lane=((k>>3)&3)*16+(n&15), e=k&7
//  Attn planes per (b,h), 16 time-tiles of 64x64:
//    row-type (Q,K): g=(t>>4)*2+(c>>5), lane=((c>>3)&3)*16+(t&15), e=c&7
//    col-type (V):   g=(c>>4)*2+(t>>5), lane=((t>>3)&3)*16+(c&15), e=t&7
// ---------------------------------------------------------------------------

// prep: one-time fp32 -> hi/lo split into A/B planes (R9, measured good)
__global__ __launch_bounds__(256) void prep_kernel(
    const float* __restrict__ wq, const float* __restrict__ wk,
    const float* __restrict__ wv, const float* __restrict__ wo,
    const float* __restrict__ x,
    unsigned short* __restrict__ WAhi, unsigned short* __restrict__ WAlo,
    unsigned short* __restrict__ XBhi, unsigned short* __restrict__ XBlo)
{
    const int w = threadIdx.x >> 6, lane = threadIdx.x & 63;
    const int l15 = lane & 15, quad = lane >> 4;
    const int task = blockIdx.x * 4 + w;

    if (task < 2048) {
        const int mtile = task >> 4, kt = task & 15;
        const int sel = mtile >> 5;
        const float* W = sel == 0 ? wq : (sel == 1 ? wk : (sel == 2 ? wv : wo));
        const int row = (mtile & 31) * 16 + l15;
        const float* p = W + (size_t)row * Cdim + kt * 32 + quad * 8;
        float f[8];
        *(float4*)&f[0] = *(const float4*)p;
        *(float4*)&f[4] = *(const float4*)(p + 4);
        bf16x8 h8, l8;
        split8(f, h8, l8);
        const size_t base = (size_t)task * 512 + lane * 8;
        *(bf16x8*)(WAhi + base) = h8;
        *(bf16x8*)(WAlo + base) = l8;
    } else {
        const int t2 = task - 2048;
        const int b = t2 >> 10, ntile = (t2 >> 4) & 63, kt = t2 & 15;
        const float* Xb = x + (size_t)b * Cdim * Tdim;
        const int n = ntile * 16 + l15;
        const int k0 = kt * 32 + quad * 8;
        float f[8];
        #pragma unroll
        for (int e = 0; e < 8; ++e) f[e] = Xb[(size_t)(k0 + e) * Tdim + n];
        bf16x8 h8, l8;
        split8(f, h8, l8);
        const size_t base = (size_t)t2 * 512 + lane * 8;
        *(bf16x8*)(XBhi + base) = h8;
        *(bf16x8*)(XBlo + base) = l8;
    }
}

// ---------------------------------------------------------------------------
// QKV GEMM: barrier-free, zero-LDS, dbuf. Wave = 64m x 32n x 512k.
// 3072 wave-jobs -> 768 blocks = 3 blocks/CU (12 waves/CU).
// XCD-clustered: 16 (b,n32) columns per XCD share B stripes in that L2.
// q rows are pre-scaled by QK_SCALE so attention scores land in exp2 domain.
// ---------------------------------------------------------------------------
__global__ __launch_bounds__(256, 3) void gemm_qkv(
    const unsigned short* __restrict__ Ahi, const unsigned short* __restrict__ Alo,
    const unsigned short* __restrict__ Bhi, const unsigned short* __restrict__ Blo,
    const float* __restrict__ bq, const float* __restrict__ bk, const float* __restrict__ bv,
    unsigned short* __restrict__ qhi, unsigned short* __restrict__ qlo,
    unsigned short* __restrict__ khi, unsigned short* __restrict__ klo,
    unsigned short* __restrict__ vhi, unsigned short* __restrict__ vlo)
{
    const int tid = threadIdx.x;
    const int w = tid >> 6, lane = tid & 63;
    const int l15 = lane & 15, quad = lane >> 4;
    const int lo8 = lane << 3;

    const int id = blockIdx.x;
    const int xcd = id & 7, slot = id >> 3;     // slot 0..95
    const int col = xcd * 16 + slot / 6;        // 0..127 = (b, n32)
    const int mg  = slot % 6;
    const int b = col >> 5, n32 = col & 31;
    const int m64 = mg * 4 + w;                 // 0..23 stacked q/k/v
    const int sel = m64 >> 3;
    const int mtb = m64 * 4;                    // mtile16 base (q:0-31 k:32-63 v:64-95)
    const int ntb = b * 64 + n32 * 2;

    f32x4 acc[4][2];
    #pragma unroll
    for (int i = 0; i < 4; ++i)
        #pragma unroll
        for (int j = 0; j < 2; ++j) acc[i][j] = (f32x4){0.f, 0.f, 0.f, 0.f};

    bf16x8 Ah[2][4], Al[2][4], Bh[2][2], Bl[2][2];
    #pragma unroll
    for (int mt = 0; mt < 4; ++mt) {
        const size_t o = (size_t)(mtb + mt) * 8192 + lo8;
        Ah[0][mt] = *(const bf16x8*)(Ahi + o);
        Al[0][mt] = *(const bf16x8*)(Alo + o);
    }
    #pragma unroll
    for (int nt = 0; nt < 2; ++nt) {
        const size_t o = (size_t)(ntb + nt) * 8192 + lo8;
        Bh[0][nt] = *(const bf16x8*)(Bhi + o);
        Bl[0][nt] = *(const bf16x8*)(Blo + o);
    }

    for (int kt = 0; kt < 16; ++kt) {
        const int cur = kt & 1, nxt = cur ^ 1;
        if (kt < 15) {
            const int kn = (kt + 1) * 512;
            #pragma unroll
            for (int mt = 0; mt < 4; ++mt) {
                const size_t o = (size_t)(mtb + mt) * 8192 + kn + lo8;
                Ah[nxt][mt] = *(const bf16x8*)(Ahi + o);
                Al[nxt][mt] = *(const bf16x8*)(Alo + o);
            }
            #pragma unroll
            for (int nt = 0; nt < 2; ++nt) {
                const size_t o = (size_t)(ntb + nt) * 8192 + kn + lo8;
                Bh[nxt][nt] = *(const bf16x8*)(Bhi + o);
                Bl[nxt][nt] = *(const bf16x8*)(Blo + o);
            }
        }
        #pragma unroll
        for (int mt = 0; mt < 4; ++mt)
            #pragma unroll
            for (int nt = 0; nt < 2; ++nt) {
                f32x4 c = acc[mt][nt];
                c = __builtin_amdgcn_mfma_f32_16x16x32_bf16(Ah[cur][mt], Bh[cur][nt], c, 0, 0, 0);
                c = __builtin_amdgcn_mfma_f32_16x16x32_bf16(Ah[cur][mt], Bl[cur][nt], c, 0, 0, 0);
                c = __builtin_amdgcn_mfma_f32_16x16x32_bf16(Al[cur][mt], Bh[cur][nt], c, 0, 0, 0);
                acc[mt][nt] = c;
            }
    }

    // ---- epilogue: D[m=quad*4+r (channel)][n=l15 (time)] -> attn planes ----
    const int head = m64 & 7;
    const size_t hbase = ((size_t)(b * Hn + head) * 16) << 12;
    if (sel < 2) {
        const float* Bv = sel == 0 ? bq : bk;
        unsigned short* ph = sel == 0 ? qhi : khi;
        unsigned short* pl = sel == 0 ? qlo : klo;
        const float qscale = sel == 0 ? QK_SCALE : 1.0f;
        #pragma unroll
        for (int mt = 0; mt < 4; ++mt) {
            const int c0 = mt * 16 + quad * 4;          // channel-in-head base
            float bb[4];
            #pragma unroll
            for (int r = 0; r < 4; ++r) bb[r] = Bv[head * 64 + c0 + r];
            const int lane_out = (((c0 >> 3) & 3) << 4) + l15;
            const int e0 = c0 & 7;                      // 0 or 4
            const int cg = c0 >> 5;
            #pragma unroll
            for (int nt = 0; nt < 2; ++nt) {
                const int tile = n32 >> 1;
                const int rhi = (n32 & 1) * 2 + nt;     // (t&63)>>4
                const int g = rhi * 2 + cg;
                const size_t off = hbase + ((size_t)tile << 12) + g * 512
                                 + (size_t)lane_out * 8 + e0;
                ushort4 h4, l4;
                #pragma unroll
                for (int r = 0; r < 4; ++r) {
                    const float v = (acc[mt][nt][r] + bb[r]) * qscale;
                    const unsigned short hh = f32_bf16_rne(v);
                    ((unsigned short*)&h4)[r] = hh;
                    ((unsigned short*)&l4)[r] = f32_bf16_rne(v - bf16_f32(hh));
                }
                *(ushort4*)(ph + off) = h4;
                *(ushort4*)(pl + off) = l4;
            }
        }
    } else {
        #pragma unroll
        for (int mt = 0; mt < 4; ++mt) {
            const int c0 = mt * 16 + quad * 4;
            float bb[4];
            #pragma unroll
            for (int r = 0; r < 4; ++r) bb[r] = bv[head * 64 + c0 + r];
            #pragma unroll
            for (int nt = 0; nt < 2; ++nt) {
                const int t = n32 * 32 + nt * 16 + l15;
                const int tile = t >> 6, jl = t & 63;
                const int jg = jl >> 5, lanej = ((jl >> 3) & 3) << 4;
                const int e = jl & 7;
                const size_t tb = hbase + ((size_t)tile << 12);
                #pragma unroll
                for (int r = 0; r < 4; ++r) {
                    const int c = c0 + r;
                    const int g = mt * 2 + jg;          // c>>4 == mt here
                    const int lane_v = lanej + (c & 15);
                    const float v = acc[mt][nt][r] + bb[r];
                    const unsigned short hh = f32_bf16_rne(v);
                    const size_t off = tb + g * 512 + (size_t)lane_v * 8 + e;
                    vhi[off] = hh;
                    vlo[off] = f32_bf16_rne(v - bf16_f32(hh));
                }
            }
        }
    }
}

// ---------------------------------------------------------------------------
// Out-projection GEMM: barrier-free, zero-LDS, dbuf. Wave = 32m x 32n x 512k.
// 2048 wave-jobs -> 512 blocks = 2 blocks/CU (every CU active).
// A = Wo rows (mtile16 96..127), B = ctx planes from attention.
// ---------------------------------------------------------------------------
__global__ __launch_bounds__(256) void gemm_out(
    const unsigned short* __restrict__ Ahi, const unsigned short* __restrict__ Alo,
    const unsigned short* __restrict__ Bhi, const unsigned short* __restrict__ Blo,
    const float* __restrict__ bo, float* __restrict__ out)
{
    const int tid = threadIdx.x;
    const int w = tid >> 6, lane = tid & 63;
    const int l15 = lane & 15, quad = lane >> 4;
    const int lo8 = lane << 3;

    const int id = blockIdx.x;
    const int xcd = id & 7, slot = id >> 3;     // slot 0..63
    const int col = xcd * 16 + (slot >> 2);     // 0..127 = (b, n32)
    const int mg  = slot & 3;
    const int b = col >> 5, n32 = col & 31;
    const int m32 = mg * 4 + w;                 // 0..15
    const int mtb = 96 + m32 * 2;               // Wo mtile16 base
    const int ntb = b * 64 + n32 * 2;

    f32x4 acc[2][2];
    #pragma unroll
    for (int i = 0; i < 2; ++i)
        #pragma unroll
        for (int j = 0; j < 2; ++j) acc[i][j] = (f32x4){0.f, 0.f, 0.f, 0.f};

    bf16x8 Ah[2][2], Al[2][2], Bh[2][2], Bl[2][2];
    #pragma unroll
    for (int mt = 0; mt < 2; ++mt) {
        const size_t o = (size_t)(mtb + mt) * 8192 + lo8;
        Ah[0][mt] = *(const bf16x8*)(Ahi + o);
        Al[0][mt] = *(const bf16x8*)(Alo + o);
    }
    #pragma unroll
    for (int nt = 0; nt < 2; ++nt) {
        const size_t o = (size_t)(ntb + nt) * 8192 + lo8;
        Bh[0][nt] = *(const bf16x8*)(Bhi + o);
        Bl[0][nt] = *(const bf16x8*)(Blo + o);
    }

    for (int kt = 0; kt < 16; ++kt) {
        const int cur = kt & 1, nxt = cur ^ 1;
        if (kt < 15) {
            const int kn = (kt + 1) * 512;
            #pragma unroll
            for (int mt = 0; mt < 2; ++mt) {
                const size_t o = (size_t)(mtb + mt) * 8192 + kn + lo8;
                Ah[nxt][mt] = *(const bf16x8*)(Ahi + o);
                Al[nxt][mt] = *(const bf16x8*)(Alo + o);
            }
            #pragma unroll
            for (int nt = 0; nt < 2; ++nt) {
                const size_t o = (size_t)(ntb + nt) * 8192 + kn + lo8;
                Bh[nxt][nt] = *(const bf16x8*)(Bhi + o);
                Bl[nxt][nt] = *(const bf16x8*)(Blo + o);
            }
        }
        #pragma unroll
        for (int mt = 0; mt < 2; ++mt)
            #pragma unroll
            for (int nt = 0; nt < 2; ++nt) {
                f32x4 c = acc[mt][nt];
                c = __builtin_amdgcn_mfma_f32_16x16x32_bf16(Ah[cur][mt], Bh[cur][nt], c, 0, 0, 0);
                c = __builtin_amdgcn_mfma_f32_16x16x32_bf16(Ah[cur][mt], Bl[cur][nt], c, 0, 0, 0);
                c = __builtin_amdgcn_mfma_f32_16x16x32_bf16(Al[cur][mt], Bh[cur][nt], c, 0, 0, 0);
                acc[mt][nt] = c;
            }
    }

    float* Ob = out + (size_t)b * Cdim * Tdim;
    #pragma unroll
    for (int mt = 0; mt < 2; ++mt) {
        const int m = m32 * 32 + mt * 16 + quad * 4;
        float bb[4];
        #pragma unroll
        for (int r = 0; r < 4; ++r) bb[r] = bo[m + r];
        #pragma unroll
        for (int nt = 0; nt < 2; ++nt) {
            const int t = n32 * 32 + nt * 16 + l15;
            #pragma unroll
            for (int r = 0; r < 4; ++r)
                Ob[(size_t)(m + r) * Tdim + t] = acc[mt][nt][r] + bb[r];
        }
    }
}

// ---------------------------------------------------------------------------
// Barrier-free MFMA flash attention (R2 structure: 256 thr, 4 waves, 16 KV
// tiles/wave) + ILP round: K-fragment register double-buffer across tiles
// (ks=0 prefetched a full tile early; ks=1 hoisted above the ks=0 MFMA
// cluster) + s_setprio around MFMA clusters. t-loop hand-unrolled x2 with
// named A/B buffers (rule #20: no runtime-indexed frag arrays).
// ---------------------------------------------------------------------------
__global__ __launch_bounds__(256) void attn_mfma(
    const unsigned short* __restrict__ qhi, const unsigned short* __restrict__ qlo,
    const unsigned short* __restrict__ khi, const unsigned short* __restrict__ klo,
    const unsigned short* __restrict__ vhi, const unsigned short* __restrict__ vlo,
    const float* __restrict__ ek,   // [9,64]
    const float* __restrict__ ev,   // [9,64]
    unsigned short* __restrict__ cxhi, unsigned short* __restrict__ cxlo)
{
    __shared__ alignas(16) unsigned short psh[4096], psl[4096];
    __shared__ float rk[576];       // rel-k logits (exp2 domain via q scale)
    __shared__ float evs[576];
    __shared__ float bandp[576];    // f32 post-exp P band values, wave-private rows

    const int tid = threadIdx.x;
    int it, h, b;
    {
        const int n = blockIdx.x;
        const int xcd = n & 7, slot = n >> 3;
        const int pair = (xcd << 2) | (slot >> 4);
        it = slot & 15;
        b = pair >> 3;
        h = pair & 7;
    }
    const int i0 = it * 64;
    const int lane = tid & 63, w = tid >> 6;
    const int l15 = lane & 15, quad = lane >> 4;
    const int m_blk = w * 16 + l15;
    const int lo8 = lane << 3;

    const size_t bh16 = (size_t)(b * Hn + h) * 16;

    bf16x8 qfh[2], qfl[2];
    {
        const unsigned short* qth = qhi + ((bh16 + it) << 12);
        const unsigned short* qtl = qlo + ((bh16 + it) << 12);
        #pragma unroll
        for (int ks = 0; ks < 2; ++ks) {
            qfh[ks] = *(const bf16x8*)(qth + (((w << 1) | ks) << 9) + lo8);
            qfl[ks] = *(const bf16x8*)(qtl + (((w << 1) | ks) << 9) + lo8);
        }
    }

    const unsigned short* kh0 = khi + (bh16 << 12);
    const unsigned short* kl0 = klo + (bh16 << 12);
    const unsigned short* vh0 = vhi + (bh16 << 12);
    const unsigned short* vl0 = vlo + (bh16 << 12);

    // K ks=0 register double-buffer: prologue loads tile 0 (long latency,
    // overlaps the rel-k MFMA + evs fill + barrier below)
    bf16x8 kAh[4], kAl[4], kBh[4], kBl[4];
    #pragma unroll
    for (int jt = 0; jt < 4; ++jt) {
        kAh[jt] = *(const bf16x8*)(kh0 + ((jt << 1) << 9) + lo8);
        kAl[jt] = *(const bf16x8*)(kl0 + ((jt << 1) << 9) + lo8);
    }

    bf16x8 ekh[2], ekl[2];
    #pragma unroll
    for (int ks = 0; ks < 2; ++ks) {
        #pragma unroll
        for (int j = 0; j < 8; ++j) { ekh[ks][j] = 0; ekl[ks][j] = 0; }
        if (l15 < 9) {
            #pragma unroll
            for (int j = 0; j < 8; ++j) {
                const float v = ek[l15 * 64 + ks * 32 + quad * 8 + j];
                const unsigned short hh = f32_bf16_rne(v);
                ekh[ks][j] = (short)hh;
                ekl[ks][j] = (short)f32_bf16_rne(v - bf16_f32(hh));
            }
        }
    }

    {
        f32x4 rkD = (f32x4){0.f, 0.f, 0.f, 0.f};
        #pragma unroll
        for (int ks = 0; ks < 2; ++ks) {
            rkD = __builtin_amdgcn_mfma_f32_16x16x32_bf16(qfh[ks], ekh[ks], rkD, 0, 0, 0);
            rkD = __builtin_amdgcn_mfma_f32_16x16x32_bf16(qfh[ks], ekl[ks], rkD, 0, 0, 0);
            rkD = __builtin_amdgcn_mfma_f32_16x16x32_bf16(qfl[ks], ekh[ks], rkD, 0, 0, 0);
        }
        if (l15 < 9) {
            // q is pre-scaled -> rkD already carries QK_SCALE
            #pragma unroll
            for (int r = 0; r < 4; ++r)
                rk[(w * 16 + quad * 4 + r) * 9 + l15] = rkD[r];
        }
    }
    for (int idx = tid; idx < 576; idx += 256) evs[idx] = ev[idx];
    __syncthreads();   // the ONLY barrier

    float m_run = -1e30f, l_run = 0.f;
    f32x4 Oc[4];
    #pragma unroll
    for (int ct = 0; ct < 4; ++ct) Oc[ct] = (f32x4){0.f, 0.f, 0.f, 0.f};

    // one KV tile step; kch/kcl = this tile's prefetched ks=0 K frags,
    // knh/knl = buffer to prefetch tile t+1's ks=0 K frags into.
    auto tile_step = [&](int t, bf16x8 (&kch)[4], bf16x8 (&kcl)[4],
                         bf16x8 (&knh)[4], bf16x8 (&knl)[4], bool pf) {
        const int j0 = t << 6;
        const size_t tb = (size_t)t << 12;
        const unsigned short* kht = kh0 + tb;
        const unsigned short* klt = kl0 + tb;
        const unsigned short* vht = vh0 + tb;
        const unsigned short* vlt = vl0 + tb;

        // V tile frags (consumed after softmax -> natural slack)
        bf16x8 vbh[2][4], vbl[2][4];
        #pragma unroll
        for (int ks = 0; ks < 2; ++ks)
            #pragma unroll
            for (int ct = 0; ct < 4; ++ct) {
                vbh[ks][ct] = *(const bf16x8*)(vht + (((ct << 1) | ks) << 9) + lo8);
                vbl[ks][ct] = *(const bf16x8*)(vlt + (((ct << 1) | ks) << 9) + lo8);
            }
        // this tile's ks=1 K frags (covered by the ks=0 MFMA cluster)
        bf16x8 a1h[4], a1l[4];
        #pragma unroll
        for (int jt = 0; jt < 4; ++jt) {
            a1h[jt] = *(const bf16x8*)(kht + (((jt << 1) | 1) << 9) + lo8);
            a1l[jt] = *(const bf16x8*)(klt + (((jt << 1) | 1) << 9) + lo8);
        }
        // prefetch next tile's ks=0 K frags (covered by softmax + PV)
        if (pf) {
            #pragma unroll
            for (int jt = 0; jt < 4; ++jt) {
                knh[jt] = *(const bf16x8*)(kht + 4096 + ((jt << 1) << 9) + lo8);
                knl[jt] = *(const bf16x8*)(klt + 4096 + ((jt << 1) << 9) + lo8);
            }
        }

        f32x4 Sc[4];
        #pragma unroll
        for (int jt = 0; jt < 4; ++jt) Sc[jt] = (f32x4){0.f, 0.f, 0.f, 0.f};
        __builtin_amdgcn_s_setprio(1);
        #pragma unroll
        for (int jt = 0; jt < 4; ++jt) {
            Sc[jt] = __builtin_amdgcn_mfma_f32_16x16x32_bf16(kch[jt], qfh[0], Sc[jt], 0, 0, 0);
            Sc[jt] = __builtin_amdgcn_mfma_f32_16x16x32_bf16(kch[jt], qfl[0], Sc[jt], 0, 0, 0);
            Sc[jt] = __builtin_amdgcn_mfma_f32_16x16x32_bf16(kcl[jt], qfh[0], Sc[jt], 0, 0, 0);
        }
        #pragma unroll
        for (int jt = 0; jt < 4; ++jt) {
            Sc[jt] = __builtin_amdgcn_mfma_f32_16x16x32_bf16(a1h[jt], qfh[1], Sc[jt], 0, 0, 0);
            Sc[jt] = __builtin_amdgcn_mfma_f32_16x16x32_bf16(a1h[jt], qfl[1], Sc[jt], 0, 0, 0);
            Sc[jt] = __builtin_amdgcn_mfma_f32_16x16x32_bf16(a1l[jt], qfh[1], Sc[jt], 0, 0, 0);
        }
        __builtin_amdgcn_s_setprio(0);

        const int dt = j0 - i0;
        const bool diag = (dt >= -67 && dt <= 67);
        if (diag) {
            #pragma unroll
            for (int jt = 0; jt < 4; ++jt) {
                const int db = dt + jt * 16 + quad * 4 - m_blk;
                #pragma unroll
                for (int r = 0; r < 4; ++r) {
                    const int d = db + r;
                    if ((unsigned)(d + 4) <= 8u) Sc[jt][r] += rk[m_blk * 9 + d + 4];
                }
            }
        }

        // row max (tree)
        const float mt = fmaxf(
            fmaxf(fmaxf(fmaxf(Sc[0][0], Sc[0][1]), fmaxf(Sc[0][2], Sc[0][3])),
                  fmaxf(fmaxf(Sc[1][0], Sc[1][1]), fmaxf(Sc[1][2], Sc[1][3]))),
            fmaxf(fmaxf(fmaxf(Sc[2][0], Sc[2][1]), fmaxf(Sc[2][2], Sc[2][3])),
                  fmaxf(fmaxf(Sc[3][0], Sc[3][1]), fmaxf(Sc[3][2], Sc[3][3]))));
        float mr = fmaxf(mt, __shfl_xor(mt, 16));
        mr = fmaxf(mr, __shfl_xor(mr, 32));
        const float mn = fmaxf(m_run, mr);
        const float alpha = __builtin_amdgcn_exp2f(m_run - mn);

        #pragma unroll
        for (int jt = 0; jt < 4; ++jt)
            #pragma unroll
            for (int r = 0; r < 4; ++r)
                Sc[jt][r] = __builtin_amdgcn_exp2f(Sc[jt][r] - mn);

        float rs = ((Sc[0][0] + Sc[0][1]) + (Sc[0][2] + Sc[0][3]))
                 + ((Sc[1][0] + Sc[1][1]) + (Sc[1][2] + Sc[1][3]))
                 + ((Sc[2][0] + Sc[2][1]) + (Sc[2][2] + Sc[2][3]))
                 + ((Sc[3][0] + Sc[3][1]) + (Sc[3][2] + Sc[3][3]));
        rs += __shfl_xor(rs, 16);
        rs += __shfl_xor(rs, 32);
        l_run = l_run * alpha + rs;
        m_run = mn;

        // f32 band scatter for rel-v (wave-private rows, read after PV)
        if (diag) {
            #pragma unroll
            for (int jt = 0; jt < 4; ++jt) {
                const int db = dt + jt * 16 + quad * 4 - m_blk;
                #pragma unroll
                for (int r = 0; r < 4; ++r) {
                    const int d = db + r;
                    if ((unsigned)(d + 4) <= 8u) bandp[m_blk * 9 + d + 4] = Sc[jt][r];
                }
            }
        }

        #pragma unroll
        for (int jt = 0; jt < 4; ++jt) {
            ushort4 ph, pl;
            ph.x = f32_bf16_rne(Sc[jt][0]); pl.x = f32_bf16_rne(Sc[jt][0] - bf16_f32(ph.x));
            ph.y = f32_bf16_rne(Sc[jt][1]); pl.y = f32_bf16_rne(Sc[jt][1] - bf16_f32(ph.y));
            ph.z = f32_bf16_rne(Sc[jt][2]); pl.z = f32_bf16_rne(Sc[jt][2] - bf16_f32(ph.z));
            ph.w = f32_bf16_rne(Sc[jt][3]); pl.w = f32_bf16_rne(Sc[jt][3] - bf16_f32(ph.w));
            const int o = sw(m_blk, jt * 16 + quad * 4);
            *(ushort4*)&psh[o] = ph;
            *(ushort4*)&psl[o] = pl;
        }
        // no barrier: wave reads only its own 16 P rows

        const float al0 = __shfl(alpha, quad * 4 + 0);
        const float al1 = __shfl(alpha, quad * 4 + 1);
        const float al2 = __shfl(alpha, quad * 4 + 2);
        const float al3 = __shfl(alpha, quad * 4 + 3);
        #pragma unroll
        for (int ct = 0; ct < 4; ++ct) {
            Oc[ct][0] *= al0; Oc[ct][1] *= al1; Oc[ct][2] *= al2; Oc[ct][3] *= al3;
        }
        __builtin_amdgcn_s_setprio(1);
        #pragma unroll
        for (int ks = 0; ks < 2; ++ks) {
            bf16x8 pah = fragld(psh, m_blk, ks, quad);
            bf16x8 pal = fragld(psl, m_blk, ks, quad);
            #pragma unroll
            for (int ct = 0; ct < 4; ++ct) {
                Oc[ct] = __builtin_amdgcn_mfma_f32_16x16x32_bf16(pah, vbh[ks][ct], Oc[ct], 0, 0, 0);
                Oc[ct] = __builtin_amdgcn_mfma_f32_16x16x32_bf16(pah, vbl[ks][ct], Oc[ct], 0, 0, 0);
                Oc[ct] = __builtin_amdgcn_mfma_f32_16x16x32_bf16(pal, vbh[ks][ct], Oc[ct], 0, 0, 0);
            }
        }
        __builtin_amdgcn_s_setprio(0);

        if (diag) {
            #pragma unroll
            for (int r = 0; r < 4; ++r) {
                const int mrow = w * 16 + quad * 4 + r;
                const int ig = i0 + mrow;
                #pragma unroll
                for (int e = 0; e < 9; ++e) {
                    const int jl = ig + e - 4 - j0;
                    if ((unsigned)jl < 64u) {
                        const float p = bandp[mrow * 9 + e];   // f32 broadcast read
                        #pragma unroll
                        for (int ct = 0; ct < 4; ++ct)
                            Oc[ct][r] += p * evs[e * 64 + ct * 16 + l15];
                    }
                }
            }
        }
    };

    #pragma unroll 1
    for (int t2 = 0; t2 < 16; t2 += 2) {
        tile_step(t2,     kAh, kAl, kBh, kBl, true);
        tile_step(t2 + 1, kBh, kBl, kAh, kAl, t2 + 2 < 16);
    }

    // ---- epilogue: normalize, write ctx B-operand frag-major hi/lo planes ----
    const float rlv = 1.f / l_run;
    float rl[4];
    rl[0] = __shfl(rlv, quad * 4 + 0);
    rl[1] = __shfl(rlv, quad * 4 + 1);
    rl[2] = __shfl(rlv, quad * 4 + 2);
    rl[3] = __shfl(rlv, quad * 4 + 3);
    const int ntile16 = it * 4 + w;
    const int e = l15 & 7;
    #pragma unroll
    for (int ct = 0; ct < 4; ++ct) {
        const int cl = ct * 16 + l15;                    // channel within head
        const int ktc = h * 2 + (cl >> 5);
        const int lane_c = (((ct * 2 + (l15 >> 3)) & 3) << 4) + quad * 4;   // + r
        const size_t base = (((size_t)(b * 64 + ntile16)) * 16 + ktc) * 512;
        #pragma unroll
        for (int r = 0; r < 4; ++r) {
            const float v = Oc[ct][r] * rl[r];
            const unsigned short hh = f32_bf16_rne(v);
            const size_t off = base + (size_t)(lane_c + r) * 8 + e;
            cxhi[off] = hh;
            cxlo[off] = f32_bf16_rne(v - bf16_f32(hh));
        }
    }
}

// ---------------------------------------------------------------------------
extern "C" void kernel_launch(void* const* d_in, const int* in_sizes, int n_in,
                              void* d_out, int out_size, void* d_ws, size_t ws_size,
                              hipStream_t stream) {
    const float* x  = (const float*)d_in[0];
    const float* wq = (const float*)d_in[1];
    const float* bq = (const float*)d_in[2];
    const float* wk = (const float*)d_in[3];
    const float* bk = (const float*)d_in[4];
    const float* wv = (const float*)d_in[5];
    const float* bv = (const float*)d_in[6];
    const float* wo = (const float*)d_in[7];
    const float* bo = (const float*)d_in[8];
    const float* ek = (const float*)d_in[9];
    const float* ev = (const float*)d_in[10];
    float* out = (float*)d_out;

    const size_t PW = 2048u * 512u;          // stacked-W plane elements
    const size_t PX = 4u * 1024u * 512u;     // X / ctx / attn plane elements
    unsigned short* WAhi = (unsigned short*)d_ws;
    unsigned short* WAlo = WAhi + PW;
    unsigned short* XBhi = WAlo + PW;
    unsigned short* XBlo = XBhi + PX;
    unsigned short* qhi  = XBlo + PX;
    unsigned short* qlo  = qhi + PX;
    unsigned short* khi  = qlo + PX;
    unsigned short* klo  = khi + PX;
    unsigned short* vhi  = klo + PX;
    unsigned short* vlo  = vhi + PX;
    unsigned short* cxhi = vlo + PX;
    unsigned short* cxlo = cxhi + PX;

    // one-time split/convert of W and X into frag-major planes
    prep_kernel<<<dim3(1536), 256, 0, stream>>>(
        wq, wk, wv, wo, x, WAhi, WAlo, XBhi, XBlo);

    // QKV projection: 768 blocks (3/CU), barrier-free dbuf -> attn planes
    gemm_qkv<<<dim3(768), 256, 0, stream>>>(
        WAhi, WAlo, XBhi, XBlo, bq, bk, bv,
        qhi, qlo, khi, klo, vhi, vlo);

    // barrier-free MFMA flash attention -> ctx B-operand planes
    attn_mfma<<<dim3(512), 256, 0, stream>>>(
        qhi, qlo, khi, klo, vhi, vlo, ek, ev, cxhi, cxlo);

    // output projection: 512 blocks (2/CU), A=Wo, B=ctx -> natural fp32 out
    gemm_out<<<dim3(512), 256, 0, stream>>>(
        WAhi, WAlo, cxhi, cxlo, bo, out);
}

// Round 6
// 162.057 us; speedup vs baseline: 1.3324x; 1.1833x over previous
//
#include <hip/hip_runtime.h>
#include <hip/hip_bf16.h>

// Problem constants (B, C, T, H, KC, WIN) = (4, 512, 1024, 8, 64, 4)
#define Bdim 4
#define Cdim 512
#define Tdim 1024
#define Hn   8
#define KCd  64

// softmax scale folded into q: 1/sqrt(KC) * log2(e) -> scores in exp2 domain
#define QK_SCALE 0.18033688011112042f

typedef __attribute__((ext_vector_type(8))) short bf16x8;   // 8 bf16 = 4 VGPR
typedef __attribute__((ext_vector_type(4))) float f32x4;    // MFMA C/D

__device__ __forceinline__ unsigned short f32_bf16_rne(float f) {
    unsigned u = __float_as_uint(f);
    u += 0x7FFFu + ((u >> 16) & 1u);
    return (unsigned short)(u >> 16);
}
__device__ __forceinline__ float bf16_f32(unsigned short h) {
    return __uint_as_float(((unsigned)h) << 16);
}
__device__ __forceinline__ void split8(const float* f, bf16x8& h8, bf16x8& l8) {
    #pragma unroll
    for (int e = 0; e < 8; ++e) {
        const unsigned short hh = f32_bf16_rne(f[e]);
        h8[e] = (short)hh;
        l8[e] = (short)f32_bf16_rne(f[e] - bf16_f32(hh));
    }
}

// LDS 64x64 tile XOR swizzle (only attention's P round-trip)
__device__ __forceinline__ int sw(int row, int col) {
    return (row << 6) + ((((col >> 3) ^ (row & 7)) << 3) | (col & 7));
}
__device__ __forceinline__ bf16x8 fragld(const unsigned short* a, int row, int kstep, int quad) {
    return *(const bf16x8*)&a[(row << 6) + ((((kstep << 2) | quad) ^ (row & 7)) << 3)];
}

// ---------------------------------------------------------------------------
// FRAG-MAJOR plane layouts (hi/lo pre-split), as validated in R8/R9:
//  A-plane (stacked [wq;wk;wv;wo], 2048 rows x 512 k):
//    [mtile16:128][kt:16][lane:64][e:8]; elem(m,k): lane=((k>>3)&3)*16+(m&15), e=k&7
//  B-plane (X / ctx, per batch n=1024, k=512):
//    [b*64+ntile16][kt:16][lane:64][e:8]; elem(n,k): lane=((k>>3)&3)*16+(n&15), e=k&7
//  Attn planes per (b,h), 16 time-tiles of 64x64:
//    row-type (Q,K): g=(t>>4)*2+(c>>5), lane=((c>>3)&3)*16+(t&15), e=c&7
//    col-type (V):   g=(c>>4)*2+(t>>5), lane=((t>>3)&3)*16+(c&15), e=t&7
// ---------------------------------------------------------------------------

// prep: one-time fp32 -> hi/lo split into A/B planes (R9, measured good)
__global__ __launch_bounds__(256) void prep_kernel(
    const float* __restrict__ wq, const float* __restrict__ wk,
    const float* __restrict__ wv, const float* __restrict__ wo,
    const float* __restrict__ x,
    unsigned short* __restrict__ WAhi, unsigned short* __restrict__ WAlo,
    unsigned short* __restrict__ XBhi, unsigned short* __restrict__ XBlo)
{
    const int w = threadIdx.x >> 6, lane = threadIdx.x & 63;
    const int l15 = lane & 15, quad = lane >> 4;
    const int task = blockIdx.x * 4 + w;

    if (task < 2048) {
        const int mtile = task >> 4, kt = task & 15;
        const int sel = mtile >> 5;
        const float* W = sel == 0 ? wq : (sel == 1 ? wk : (sel == 2 ? wv : wo));
        const int row = (mtile & 31) * 16 + l15;
        const float* p = W + (size_t)row * Cdim + kt * 32 + quad * 8;
        float f[8];
        *(float4*)&f[0] = *(const float4*)p;
        *(float4*)&f[4] = *(const float4*)(p + 4);
        bf16x8 h8, l8;
        split8(f, h8, l8);
        const size_t base = (size_t)task * 512 + lane * 8;
        *(bf16x8*)(WAhi + base) = h8;
        *(bf16x8*)(WAlo + base) = l8;
    } else {
        const int t2 = task - 2048;
        const int b = t2 >> 10, ntile = (t2 >> 4) & 63, kt = t2 & 15;
        const float* Xb = x + (size_t)b * Cdim * Tdim;
        const int n = ntile * 16 + l15;
        const int k0 = kt * 32 + quad * 8;
        float f[8];
        #pragma unroll
        for (int e = 0; e < 8; ++e) f[e] = Xb[(size_t)(k0 + e) * Tdim + n];
        bf16x8 h8, l8;
        split8(f, h8, l8);
        const size_t base = (size_t)t2 * 512 + lane * 8;
        *(bf16x8*)(XBhi + base) = h8;
        *(bf16x8*)(XBlo + base) = l8;
    }
}

// ---------------------------------------------------------------------------
// QKV GEMM, R6: A-SHARED block. Block = one m64-group x four n32-columns
// (4 waves, each 64m x 32n). A stripe is block-uniform -> staged via 16KB
// LDS dbuf (each wave stages one mtile; T14 split: global loads issued
// before the MFMA cluster, ds_write after). B per-wave in registers.
// Per-block L2 traffic per kt: 24KB (was 48KB). 768 blocks = 3/CU.
// q rows pre-scaled by QK_SCALE so attention scores land in exp2 domain.
// ---------------------------------------------------------------------------
__global__ __launch_bounds__(256, 3) void gemm_qkv(
    const unsigned short* __restrict__ Ahi, const unsigned short* __restrict__ Alo,
    const unsigned short* __restrict__ Bhi, const unsigned short* __restrict__ Blo,
    const float* __restrict__ bq, const float* __restrict__ bk, const float* __restrict__ bv,
    unsigned short* __restrict__ qhi, unsigned short* __restrict__ qlo,
    unsigned short* __restrict__ khi, unsigned short* __restrict__ klo,
    unsigned short* __restrict__ vhi, unsigned short* __restrict__ vlo)
{
    __shared__ alignas(16) unsigned short As[2][4][2][512];  // [buf][mt][hi/lo][512]

    const int tid = threadIdx.x;
    const int w = tid >> 6, lane = tid & 63;
    const int l15 = lane & 15, quad = lane >> 4;
    const int lo8 = lane << 3;

    const int id = blockIdx.x;
    const int xcd = id & 7, slot = id >> 3;     // slot 0..95
    const int m64 = slot >> 2;                  // 0..23, block-uniform
    const int col128 = xcd * 4 + (slot & 3);    // 0..31 (4 columns hot per XCD L2)
    const int col = col128 * 4 + w;             // 0..127 = (b, n32), per wave
    const int b = col >> 5, n32 = col & 31;     // b block-uniform (col128*4 aligned)
    const int sel = m64 >> 3;
    const int mtb = m64 * 4;                    // mtile16 base (q:0-31 k:32-63 v:64-95)
    const int ntb = b * 64 + n32 * 2;

    // this wave stages mtile mtb+w (hi+lo) each kt
    const unsigned short* Asrc_h = Ahi + (size_t)(mtb + w) * 8192 + lo8;
    const unsigned short* Asrc_l = Alo + (size_t)(mtb + w) * 8192 + lo8;

    f32x4 acc[4][2];
    #pragma unroll
    for (int i = 0; i < 4; ++i)
        #pragma unroll
        for (int j = 0; j < 2; ++j) acc[i][j] = (f32x4){0.f, 0.f, 0.f, 0.f};

    bf16x8 Bh[2][2], Bl[2][2];
    #pragma unroll
    for (int nt = 0; nt < 2; ++nt) {
        const size_t o = (size_t)(ntb + nt) * 8192 + lo8;
        Bh[0][nt] = *(const bf16x8*)(Bhi + o);
        Bl[0][nt] = *(const bf16x8*)(Blo + o);
    }
    // prologue: stage kt=0 A stripe
    *(bf16x8*)&As[0][w][0][lo8] = *(const bf16x8*)Asrc_h;
    *(bf16x8*)&As[0][w][1][lo8] = *(const bf16x8*)Asrc_l;
    __syncthreads();

    for (int kt = 0; kt < 16; ++kt) {
        const int cur = kt & 1, nxt = cur ^ 1;
        bf16x8 stgh, stgl;
        if (kt < 15) {
            const int kn = (kt + 1) * 512;
            // issue next-kt loads EARLY (latency hidden under MFMAs)
            stgh = *(const bf16x8*)(Asrc_h + kn);
            stgl = *(const bf16x8*)(Asrc_l + kn);
            #pragma unroll
            for (int nt = 0; nt < 2; ++nt) {
                const size_t o = (size_t)(ntb + nt) * 8192 + kn + lo8;
                Bh[nxt][nt] = *(const bf16x8*)(Bhi + o);
                Bl[nxt][nt] = *(const bf16x8*)(Blo + o);
            }
        }
        // A fragments from LDS (block-shared)
        bf16x8 Afh[4], Afl[4];
        #pragma unroll
        for (int mt = 0; mt < 4; ++mt) {
            Afh[mt] = *(const bf16x8*)&As[cur][mt][0][lo8];
            Afl[mt] = *(const bf16x8*)&As[cur][mt][1][lo8];
        }
        #pragma unroll
        for (int mt = 0; mt < 4; ++mt)
            #pragma unroll
            for (int nt = 0; nt < 2; ++nt) {
                f32x4 c = acc[mt][nt];
                c = __builtin_amdgcn_mfma_f32_16x16x32_bf16(Afh[mt], Bh[cur][nt], c, 0, 0, 0);
                c = __builtin_amdgcn_mfma_f32_16x16x32_bf16(Afh[mt], Bl[cur][nt], c, 0, 0, 0);
                c = __builtin_amdgcn_mfma_f32_16x16x32_bf16(Afl[mt], Bh[cur][nt], c, 0, 0, 0);
                acc[mt][nt] = c;
            }
        if (kt < 15) {
            // write staged A AFTER the MFMA cluster (vmcnt drains here)
            *(bf16x8*)&As[nxt][w][0][lo8] = stgh;
            *(bf16x8*)&As[nxt][w][1][lo8] = stgl;
        }
        __syncthreads();
    }

    // ---- epilogue: D[m=quad*4+r (channel)][n=l15 (time)] -> attn planes ----
    const int head = m64 & 7;
    const size_t hbase = ((size_t)(b * Hn + head) * 16) << 12;
    if (sel < 2) {
        const float* Bv = sel == 0 ? bq : bk;
        unsigned short* ph = sel == 0 ? qhi : khi;
        unsigned short* pl = sel == 0 ? qlo : klo;
        const float qscale = sel == 0 ? QK_SCALE : 1.0f;
        #pragma unroll
        for (int mt = 0; mt < 4; ++mt) {
            const int c0 = mt * 16 + quad * 4;          // channel-in-head base
            float bb[4];
            #pragma unroll
            for (int r = 0; r < 4; ++r) bb[r] = Bv[head * 64 + c0 + r];
            const int lane_out = (((c0 >> 3) & 3) << 4) + l15;
            const int e0 = c0 & 7;                      // 0 or 4
            const int cg = c0 >> 5;
            #pragma unroll
            for (int nt = 0; nt < 2; ++nt) {
                const int tile = n32 >> 1;
                const int rhi = (n32 & 1) * 2 + nt;     // (t&63)>>4
                const int g = rhi * 2 + cg;
                const size_t off = hbase + ((size_t)tile << 12) + g * 512
                                 + (size_t)lane_out * 8 + e0;
                ushort4 h4, l4;
                #pragma unroll
                for (int r = 0; r < 4; ++r) {
                    const float v = (acc[mt][nt][r] + bb[r]) * qscale;
                    const unsigned short hh = f32_bf16_rne(v);
                    ((unsigned short*)&h4)[r] = hh;
                    ((unsigned short*)&l4)[r] = f32_bf16_rne(v - bf16_f32(hh));
                }
                *(ushort4*)(ph + off) = h4;
                *(ushort4*)(pl + off) = l4;
            }
        }
    } else {
        #pragma unroll
        for (int mt = 0; mt < 4; ++mt) {
            const int c0 = mt * 16 + quad * 4;
            float bb[4];
            #pragma unroll
            for (int r = 0; r < 4; ++r) bb[r] = bv[head * 64 + c0 + r];
            #pragma unroll
            for (int nt = 0; nt < 2; ++nt) {
                const int t = n32 * 32 + nt * 16 + l15;
                const int tile = t >> 6, jl = t & 63;
                const int jg = jl >> 5, lanej = ((jl >> 3) & 3) << 4;
                const int e = jl & 7;
                const size_t tb = hbase + ((size_t)tile << 12);
                #pragma unroll
                for (int r = 0; r < 4; ++r) {
                    const int c = c0 + r;
                    const int g = mt * 2 + jg;          // c>>4 == mt here
                    const int lane_v = lanej + (c & 15);
                    const float v = acc[mt][nt][r] + bb[r];
                    const unsigned short hh = f32_bf16_rne(v);
                    const size_t off = tb + g * 512 + (size_t)lane_v * 8 + e;
                    vhi[off] = hh;
                    vlo[off] = f32_bf16_rne(v - bf16_f32(hh));
                }
            }
        }
    }
}

// ---------------------------------------------------------------------------
// Out-projection GEMM, R6: B (ctx) is block-uniform -> staged via 8KB LDS
// dbuf (each wave stages one 1KB chunk; T14 issue-early/write-late).
// A per-wave in registers. Per-block L2 traffic per kt: 20KB (was 32KB).
// 512 blocks = 2/CU.
// ---------------------------------------------------------------------------
__global__ __launch_bounds__(256) void gemm_out(
    const unsigned short* __restrict__ Ahi, const unsigned short* __restrict__ Alo,
    const unsigned short* __restrict__ Bhi, const unsigned short* __restrict__ Blo,
    const float* __restrict__ bo, float* __restrict__ out)
{
    __shared__ alignas(16) unsigned short Bs[2][2][2][512];  // [buf][nt][hi/lo][512]

    const int tid = threadIdx.x;
    const int w = tid >> 6, lane = tid & 63;
    const int l15 = lane & 15, quad = lane >> 4;
    const int lo8 = lane << 3;

    const int id = blockIdx.x;
    const int xcd = id & 7, slot = id >> 3;     // slot 0..63
    const int col = xcd * 16 + (slot >> 2);     // 0..127 = (b, n32)
    const int mg  = slot & 3;
    const int b = col >> 5, n32 = col & 31;
    const int m32 = mg * 4 + w;                 // 0..15
    const int mtb = 96 + m32 * 2;               // Wo mtile16 base
    const int ntb = b * 64 + n32 * 2;

    // this wave stages B chunk (nt = w>>1, plane = w&1) each kt
    const unsigned short* Bsrc =
        ((w & 1) ? Blo : Bhi) + (size_t)(ntb + (w >> 1)) * 8192 + lo8;

    f32x4 acc[2][2];
    #pragma unroll
    for (int i = 0; i < 2; ++i)
        #pragma unroll
        for (int j = 0; j < 2; ++j) acc[i][j] = (f32x4){0.f, 0.f, 0.f, 0.f};

    bf16x8 Ah[2][2], Al[2][2];
    #pragma unroll
    for (int mt = 0; mt < 2; ++mt) {
        const size_t o = (size_t)(mtb + mt) * 8192 + lo8;
        Ah[0][mt] = *(const bf16x8*)(Ahi + o);
        Al[0][mt] = *(const bf16x8*)(Alo + o);
    }
    // prologue: stage kt=0 B stripe
    *(bf16x8*)&Bs[0][w >> 1][w & 1][lo8] = *(const bf16x8*)Bsrc;
    __syncthreads();

    for (int kt = 0; kt < 16; ++kt) {
        const int cur = kt & 1, nxt = cur ^ 1;
        bf16x8 stg;
        if (kt < 15) {
            const int kn = (kt + 1) * 512;
            stg = *(const bf16x8*)(Bsrc + kn);
            #pragma unroll
            for (int mt = 0; mt < 2; ++mt) {
                const size_t o = (size_t)(mtb + mt) * 8192 + kn + lo8;
                Ah[nxt][mt] = *(const bf16x8*)(Ahi + o);
                Al[nxt][mt] = *(const bf16x8*)(Alo + o);
            }
        }
        bf16x8 Bfh[2], Bfl[2];
        #pragma unroll
        for (int nt = 0; nt < 2; ++nt) {
            Bfh[nt] = *(const bf16x8*)&Bs[cur][nt][0][lo8];
            Bfl[nt] = *(const bf16x8*)&Bs[cur][nt][1][lo8];
        }
        #pragma unroll
        for (int mt = 0; mt < 2; ++mt)
            #pragma unroll
            for (int nt = 0; nt < 2; ++nt) {
                f32x4 c = acc[mt][nt];
                c = __builtin_amdgcn_mfma_f32_16x16x32_bf16(Ah[cur][mt], Bfh[nt], c, 0, 0, 0);
                c = __builtin_amdgcn_mfma_f32_16x16x32_bf16(Ah[cur][mt], Bfl[nt], c, 0, 0, 0);
                c = __builtin_amdgcn_mfma_f32_16x16x32_bf16(Al[cur][mt], Bfh[nt], c, 0, 0, 0);
                acc[mt][nt] = c;
            }
        if (kt < 15) {
            *(bf16x8*)&Bs[nxt][w >> 1][w & 1][lo8] = stg;
        }
        __syncthreads();
    }

    float* Ob = out + (size_t)b * Cdim * Tdim;
    #pragma unroll
    for (int mt = 0; mt < 2; ++mt) {
        const int m = m32 * 32 + mt * 16 + quad * 4;
        float bb[4];
        #pragma unroll
        for (int r = 0; r < 4; ++r) bb[r] = bo[m + r];
        #pragma unroll
        for (int nt = 0; nt < 2; ++nt) {
            const int t = n32 * 32 + nt * 16 + l15;
            #pragma unroll
            for (int r = 0; r < 4; ++r)
                Ob[(size_t)(m + r) * Tdim + t] = acc[mt][nt][r] + bb[r];
        }
    }
}

// ---------------------------------------------------------------------------
// Barrier-free MFMA flash attention (R2 version, measured 57 us — reverted
// exactly after R3/R4 split-KV and R5 ILP experiments regressed):
//  - scores arrive pre-scaled into exp2 domain (QK_SCALE folded into q)
//  - __builtin_amdgcn_exp2f drops __expf's internal mul
//  - f32 bandp LDS for the rel-v diag: 1 broadcast read vs 2 u16 reads + cvts
// ---------------------------------------------------------------------------
__global__ __launch_bounds__(256) void attn_mfma(
    const unsigned short* __restrict__ qhi, const unsigned short* __restrict__ qlo,
    const unsigned short* __restrict__ khi, const unsigned short* __restrict__ klo,
    const unsigned short* __restrict__ vhi, const unsigned short* __restrict__ vlo,
    const float* __restrict__ ek,   // [9,64]
    const float* __restrict__ ev,   // [9,64]
    unsigned short* __restrict__ cxhi, unsigned short* __restrict__ cxlo)
{
    __shared__ alignas(16) unsigned short psh[4096], psl[4096];
    __shared__ float rk[576];       // rel-k logits (already exp2-domain via q scale)
    __shared__ float evs[576];
    __shared__ float bandp[576];    // f32 post-exp P band values, wave-private rows

    const int tid = threadIdx.x;
    int it, h, b;
    {
        const int n = blockIdx.x;
        const int xcd = n & 7, slot = n >> 3;
        const int pair = (xcd << 2) | (slot >> 4);
        it = slot & 15;
        b = pair >> 3;
        h = pair & 7;
    }
    const int i0 = it * 64;
    const int lane = tid & 63, w = tid >> 6;
    const int l15 = lane & 15, quad = lane >> 4;
    const int m_blk = w * 16 + l15;
    const int lo8 = lane << 3;

    const size_t bh16 = (size_t)(b * Hn + h) * 16;

    bf16x8 qfh[2], qfl[2];
    {
        const unsigned short* qth = qhi + ((bh16 + it) << 12);
        const unsigned short* qtl = qlo + ((bh16 + it) << 12);
        #pragma unroll
        for (int ks = 0; ks < 2; ++ks) {
            qfh[ks] = *(const bf16x8*)(qth + (((w << 1) | ks) << 9) + lo8);
            qfl[ks] = *(const bf16x8*)(qtl + (((w << 1) | ks) << 9) + lo8);
        }
    }

    bf16x8 ekh[2], ekl[2];
    #pragma unroll
    for (int ks = 0; ks < 2; ++ks) {
        #pragma unroll
        for (int j = 0; j < 8; ++j) { ekh[ks][j] = 0; ekl[ks][j] = 0; }
        if (l15 < 9) {
            #pragma unroll
            for (int j = 0; j < 8; ++j) {
                const float v = ek[l15 * 64 + ks * 32 + quad * 8 + j];
                const unsigned short hh = f32_bf16_rne(v);
                ekh[ks][j] = (short)hh;
                ekl[ks][j] = (short)f32_bf16_rne(v - bf16_f32(hh));
            }
        }
    }

    {
        f32x4 rkD = (f32x4){0.f, 0.f, 0.f, 0.f};
        #pragma unroll
        for (int ks = 0; ks < 2; ++ks) {
            rkD = __builtin_amdgcn_mfma_f32_16x16x32_bf16(qfh[ks], ekh[ks], rkD, 0, 0, 0);
            rkD = __builtin_amdgcn_mfma_f32_16x16x32_bf16(qfh[ks], ekl[ks], rkD, 0, 0, 0);
            rkD = __builtin_amdgcn_mfma_f32_16x16x32_bf16(qfl[ks], ekh[ks], rkD, 0, 0, 0);
        }
        if (l15 < 9) {
            // q is pre-scaled -> rkD already carries QK_SCALE
            #pragma unroll
            for (int r = 0; r < 4; ++r)
                rk[(w * 16 + quad * 4 + r) * 9 + l15] = rkD[r];
        }
    }
    for (int idx = tid; idx < 576; idx += 256) evs[idx] = ev[idx];
    __syncthreads();   // the ONLY barrier

    float m_run = -1e30f, l_run = 0.f;
    f32x4 Oc[4];
    #pragma unroll
    for (int ct = 0; ct < 4; ++ct) Oc[ct] = (f32x4){0.f, 0.f, 0.f, 0.f};

    const unsigned short* kh0 = khi + (bh16 << 12);
    const unsigned short* kl0 = klo + (bh16 << 12);
    const unsigned short* vh0 = vhi + (bh16 << 12);
    const unsigned short* vl0 = vlo + (bh16 << 12);

    for (int t = 0; t < 16; ++t) {
        const int j0 = t << 6;
        const size_t tb = (size_t)t << 12;
        const unsigned short* kht = kh0 + tb;
        const unsigned short* klt = kl0 + tb;
        const unsigned short* vht = vh0 + tb;
        const unsigned short* vlt = vl0 + tb;

        bf16x8 vbh[2][4], vbl[2][4];
        #pragma unroll
        for (int ks = 0; ks < 2; ++ks)
            #pragma unroll
            for (int ct = 0; ct < 4; ++ct) {
                vbh[ks][ct] = *(const bf16x8*)(vht + (((ct << 1) | ks) << 9) + lo8);
                vbl[ks][ct] = *(const bf16x8*)(vlt + (((ct << 1) | ks) << 9) + lo8);
            }

        f32x4 Sc[4];
        #pragma unroll
        for (int jt = 0; jt < 4; ++jt) Sc[jt] = (f32x4){0.f, 0.f, 0.f, 0.f};
        #pragma unroll
        for (int ks = 0; ks < 2; ++ks) {
            bf16x8 ah[4], al[4];
            #pragma unroll
            for (int jt = 0; jt < 4; ++jt) {
                ah[jt] = *(const bf16x8*)(kht + (((jt << 1) | ks) << 9) + lo8);
                al[jt] = *(const bf16x8*)(klt + (((jt << 1) | ks) << 9) + lo8);
            }
            #pragma unroll
            for (int jt = 0; jt < 4; ++jt) {
                Sc[jt] = __builtin_amdgcn_mfma_f32_16x16x32_bf16(ah[jt], qfh[ks], Sc[jt], 0, 0, 0);
                Sc[jt] = __builtin_amdgcn_mfma_f32_16x16x32_bf16(ah[jt], qfl[ks], Sc[jt], 0, 0, 0);
                Sc[jt] = __builtin_amdgcn_mfma_f32_16x16x32_bf16(al[jt], qfh[ks], Sc[jt], 0, 0, 0);
            }
        }

        const int dt = j0 - i0;
        const bool diag = (dt >= -67 && dt <= 67);
        if (diag) {
            #pragma unroll
            for (int jt = 0; jt < 4; ++jt) {
                const int db = dt + jt * 16 + quad * 4 - m_blk;
                #pragma unroll
                for (int r = 0; r < 4; ++r) {
                    const int d = db + r;
                    if ((unsigned)(d + 4) <= 8u) Sc[jt][r] += rk[m_blk * 9 + d + 4];
                }
            }
        }

        // row max (tree)
        const float mt = fmaxf(
            fmaxf(fmaxf(fmaxf(Sc[0][0], Sc[0][1]), fmaxf(Sc[0][2], Sc[0][3])),
                  fmaxf(fmaxf(Sc[1][0], Sc[1][1]), fmaxf(Sc[1][2], Sc[1][3]))),
            fmaxf(fmaxf(fmaxf(Sc[2][0], Sc[2][1]), fmaxf(Sc[2][2], Sc[2][3])),
                  fmaxf(fmaxf(Sc[3][0], Sc[3][1]), fmaxf(Sc[3][2], Sc[3][3]))));
        float mr = fmaxf(mt, __shfl_xor(mt, 16));
        mr = fmaxf(mr, __shfl_xor(mr, 32));
        const float mn = fmaxf(m_run, mr);
        const float alpha = __builtin_amdgcn_exp2f(m_run - mn);

        #pragma unroll
        for (int jt = 0; jt < 4; ++jt)
            #pragma unroll
            for (int r = 0; r < 4; ++r)
                Sc[jt][r] = __builtin_amdgcn_exp2f(Sc[jt][r] - mn);

        float rs = ((Sc[0][0] + Sc[0][1]) + (Sc[0][2] + Sc[0][3]))
                 + ((Sc[1][0] + Sc[1][1]) + (Sc[1][2] + Sc[1][3]))
                 + ((Sc[2][0] + Sc[2][1]) + (Sc[2][2] + Sc[2][3]))
                 + ((Sc[3][0] + Sc[3][1]) + (Sc[3][2] + Sc[3][3]));
        rs += __shfl_xor(rs, 16);
        rs += __shfl_xor(rs, 32);
        l_run = l_run * alpha + rs;
        m_run = mn;

        // f32 band scatter for rel-v (wave-private rows, read after PV)
        if (diag) {
            #pragma unroll
            for (int jt = 0; jt < 4; ++jt) {
                const int db = dt + jt * 16 + quad * 4 - m_blk;
                #pragma unroll
                for (int r = 0; r < 4; ++r) {
                    const int d = db + r;
                    if ((unsigned)(d + 4) <= 8u) bandp[m_blk * 9 + d + 4] = Sc[jt][r];
                }
            }
        }

        #pragma unroll
        for (int jt = 0; jt < 4; ++jt) {
            ushort4 ph, pl;
            ph.x = f32_bf16_rne(Sc[jt][0]); pl.x = f32_bf16_rne(Sc[jt][0] - bf16_f32(ph.x));
            ph.y = f32_bf16_rne(Sc[jt][1]); pl.y = f32_bf16_rne(Sc[jt][1] - bf16_f32(ph.y));
            ph.z = f32_bf16_rne(Sc[jt][2]); pl.z = f32_bf16_rne(Sc[jt][2] - bf16_f32(ph.z));
            ph.w = f32_bf16_rne(Sc[jt][3]); pl.w = f32_bf16_rne(Sc[jt][3] - bf16_f32(ph.w));
            const int o = sw(m_blk, jt * 16 + quad * 4);
            *(ushort4*)&psh[o] = ph;
            *(ushort4*)&psl[o] = pl;
        }
        // no barrier: wave reads only its own 16 P rows

        const float al0 = __shfl(alpha, quad * 4 + 0);
        const float al1 = __shfl(alpha, quad * 4 + 1);
        const float al2 = __shfl(alpha, quad * 4 + 2);
        const float al3 = __shfl(alpha, quad * 4 + 3);
        #pragma unroll
        for (int ct = 0; ct < 4; ++ct) {
            Oc[ct][0] *= al0; Oc[ct][1] *= al1; Oc[ct][2] *= al2; Oc[ct][3] *= al3;
        }
        #pragma unroll
        for (int ks = 0; ks < 2; ++ks) {
            bf16x8 pah = fragld(psh, m_blk, ks, quad);
            bf16x8 pal = fragld(psl, m_blk, ks, quad);
            #pragma unroll
            for (int ct = 0; ct < 4; ++ct) {
                Oc[ct] = __builtin_amdgcn_mfma_f32_16x16x32_bf16(pah, vbh[ks][ct], Oc[ct], 0, 0, 0);
                Oc[ct] = __builtin_amdgcn_mfma_f32_16x16x32_bf16(pah, vbl[ks][ct], Oc[ct], 0, 0, 0);
                Oc[ct] = __builtin_amdgcn_mfma_f32_16x16x32_bf16(pal, vbh[ks][ct], Oc[ct], 0, 0, 0);
            }
        }

        if (diag) {
            #pragma unroll
            for (int r = 0; r < 4; ++r) {
                const int mrow = w * 16 + quad * 4 + r;
                const int ig = i0 + mrow;
                #pragma unroll
                for (int e = 0; e < 9; ++e) {
                    const int jl = ig + e - 4 - j0;
                    if ((unsigned)jl < 64u) {
                        const float p = bandp[mrow * 9 + e];   // f32 broadcast read
                        #pragma unroll
                        for (int ct = 0; ct < 4; ++ct)
                            Oc[ct][r] += p * evs[e * 64 + ct * 16 + l15];
                    }
                }
            }
        }
    }

    // ---- epilogue: normalize, write ctx B-operand frag-major hi/lo planes ----
    const float rlv = 1.f / l_run;
    float rl[4];
    rl[0] = __shfl(rlv, quad * 4 + 0);
    rl[1] = __shfl(rlv, quad * 4 + 1);
    rl[2] = __shfl(rlv, quad * 4 + 2);
    rl[3] = __shfl(rlv, quad * 4 + 3);
    const int ntile16 = it * 4 + w;
    const int e = l15 & 7;
    #pragma unroll
    for (int ct = 0; ct < 4; ++ct) {
        const int cl = ct * 16 + l15;                    // channel within head
        const int ktc = h * 2 + (cl >> 5);
        const int lane_c = (((ct * 2 + (l15 >> 3)) & 3) << 4) + quad * 4;   // + r
        const size_t base = (((size_t)(b * 64 + ntile16)) * 16 + ktc) * 512;
        #pragma unroll
        for (int r = 0; r < 4; ++r) {
            const float v = Oc[ct][r] * rl[r];
            const unsigned short hh = f32_bf16_rne(v);
            const size_t off = base + (size_t)(lane_c + r) * 8 + e;
            cxhi[off] = hh;
            cxlo[off] = f32_bf16_rne(v - bf16_f32(hh));
        }
    }
}

// ---------------------------------------------------------------------------
extern "C" void kernel_launch(void* const* d_in, const int* in_sizes, int n_in,
                              void* d_out, int out_size, void* d_ws, size_t ws_size,
                              hipStream_t stream) {
    const float* x  = (const float*)d_in[0];
    const float* wq = (const float*)d_in[1];
    const float* bq = (const float*)d_in[2];
    const float* wk = (const float*)d_in[3];
    const float* bk = (const float*)d_in[4];
    const float* wv = (const float*)d_in[5];
    const float* bv = (const float*)d_in[6];
    const float* wo = (const float*)d_in[7];
    const float* bo = (const float*)d_in[8];
    const float* ek = (const float*)d_in[9];
    const float* ev = (const float*)d_in[10];
    float* out = (float*)d_out;

    const size_t PW = 2048u * 512u;          // stacked-W plane elements
    const size_t PX = 4u * 1024u * 512u;     // X / ctx / attn plane elements
    unsigned short* WAhi = (unsigned short*)d_ws;
    unsigned short* WAlo = WAhi + PW;
    unsigned short* XBhi = WAlo + PW;
    unsigned short* XBlo = XBhi + PX;
    unsigned short* qhi  = XBlo + PX;
    unsigned short* qlo  = qhi + PX;
    unsigned short* khi  = qlo + PX;
    unsigned short* klo  = khi + PX;
    unsigned short* vhi  = klo + PX;
    unsigned short* vlo  = vhi + PX;
    unsigned short* cxhi = vlo + PX;
    unsigned short* cxlo = cxhi + PX;

    // one-time split/convert of W and X into frag-major planes
    prep_kernel<<<dim3(1536), 256, 0, stream>>>(
        wq, wk, wv, wo, x, WAhi, WAlo, XBhi, XBlo);

    // QKV projection: 768 blocks (3/CU), A-shared LDS dbuf -> attn planes
    gemm_qkv<<<dim3(768), 256, 0, stream>>>(
        WAhi, WAlo, XBhi, XBlo, bq, bk, bv,
        qhi, qlo, khi, klo, vhi, vlo);

    // barrier-free MFMA flash attention -> ctx B-operand planes
    attn_mfma<<<dim3(512), 256, 0, stream>>>(
        qhi, qlo, khi, klo, vhi, vlo, ek, ev, cxhi, cxlo);

    // output projection: 512 blocks (2/CU), B-shared LDS dbuf -> fp32 out
    gemm_out<<<dim3(512), 256, 0, stream>>>(
        WAhi, WAlo, cxhi, cxlo, bo, out);
}